// Round 17
// baseline (335.090 us; speedup 1.0000x reference)
//
#include <hip/hip_runtime.h>
#include <hip/hip_bf16.h>
#include <math.h>

// Problem constants
#define BB 2
#define TT 4096
#define DM 1024
#define DSTATE 128
#define DI 2048
#define HD 64
#define NH 32
#define DIP 4384   // 2*DI + 2*DSTATE + NH
#define CD 2304    // DI + 2*DSTATE

// Chunked scan parameters
#define NC 8
#define CL 512
#define FL 64            // SSD fine-chunk length
#define FPC (CL / FL)    // 8
#define SELEMS ((size_t)BB * NH * HD * DSTATE)   // 524288

#define NP1 4480   // DIP padded to multiple of 128 for MFMA staging
#define KSPLIT 16  // split-K factor for the dt strip GEMM

typedef __attribute__((ext_vector_type(8))) short bf16x8;
typedef __attribute__((ext_vector_type(4))) float f32x4;

__device__ inline void gload16(const void* g, void* l) {
    __builtin_amdgcn_global_load_lds(
        (const __attribute__((address_space(1))) void*)g,
        (__attribute__((address_space(3))) void*)l, 16, 0, 0);
}

__device__ inline short f2bs(float f) {
    __hip_bfloat16 h = __float2bfloat16(f);
    union { __hip_bfloat16 h; short s; } u;
    u.h = h;
    return u.s;
}
__device__ inline float b2f(short s) {
    union { float f; unsigned u; } u;
    u.u = ((unsigned)(unsigned short)s) << 16;
    return u.f;
}

// ---------------- Kernel 1: LayerNorm statistics (split-D, 256 blocks) ----------------
__global__ __launch_bounds__(256) void ln_stats_kernel(const float* __restrict__ x,
                                                       float* __restrict__ mu,
                                                       float* __restrict__ rs) {
    __shared__ float sred[2][8][32];
    int tid = threadIdx.x;
    int tl = tid & 31;
    int ds = tid >> 5;               // 0..7
    int t = (blockIdx.x & 127) * 32 + tl;
    int b = blockIdx.x >> 7;
    const float* xb = x + (size_t)b * DM * TT + (size_t)ds * 128 * TT + t;
    float s = 0.f, ss = 0.f;
#pragma unroll 8
    for (int d = 0; d < 128; d++) {
        float v = xb[(size_t)d * TT];
        s += v;
        ss += v * v;
    }
    sred[0][ds][tl] = s;
    sred[1][ds][tl] = ss;
    __syncthreads();
    if (tid < 32) {
        float st = 0.f, sst = 0.f;
#pragma unroll
        for (int q = 0; q < 8; q++) { st += sred[0][q][tid]; sst += sred[1][q][tid]; }
        float m = st * (1.f / DM);
        float var = sst * (1.f / DM) - m * m;
        int idx = b * TT + (blockIdx.x & 127) * 32 + tid;
        mu[idx] = m;
        rs[idx] = rsqrtf(var + 1e-5f);
    }
}

// ---------------- Kernel 1b: xn = LN(x) transposed to (m, k) in bf16 ----------------
__global__ __launch_bounds__(256) void xn_kernel(const float* __restrict__ x,
                                                 const float* __restrict__ mu,
                                                 const float* __restrict__ rs,
                                                 const float* __restrict__ ln_w,
                                                 const float* __restrict__ ln_b,
                                                 __hip_bfloat16* __restrict__ xn) {
    __shared__ float tile[64][65];
    int tid = threadIdx.x;
    int t0 = blockIdx.x * 64, d0 = blockIdx.y * 64, b = blockIdx.z;
#pragma unroll
    for (int i = 0; i < 64; i += 4) {
        int dl = i + (tid >> 6);
        tile[dl][tid & 63] = x[(size_t)b * DM * TT + (size_t)(d0 + dl) * TT + t0 + (tid & 63)];
    }
    __syncthreads();
#pragma unroll
    for (int i = 0; i < 64; i += 8) {
        int tl = i + (tid >> 5);
        int kk = (tid & 31) * 2;
        int m = b * TT + t0 + tl;
        float mu_m = mu[m], rs_m = rs[m];
        float v0 = (tile[kk][tl] - mu_m) * rs_m * ln_w[d0 + kk] + ln_b[d0 + kk];
        float v1 = (tile[kk + 1][tl] - mu_m) * rs_m * ln_w[d0 + kk + 1] + ln_b[d0 + kk + 1];
        __hip_bfloat162 pk;
        pk.x = __float2bfloat16(v0);
        pk.y = __float2bfloat16(v1);
        *(__hip_bfloat162*)(xn + (size_t)m * DM + d0 + kk) = pk;
    }
}

// ---------------- convert f32 -> bf16 with zero-padding ----------------
__global__ __launch_bounds__(256) void cvt_pad_kernel(const float* __restrict__ src,
                                                      __hip_bfloat16* __restrict__ dst,
                                                      int src_n, int tot_n) {
    int i = (blockIdx.x * 256 + threadIdx.x) * 4;
    if (i >= tot_n) return;
    float4 v = (i < src_n) ? *(const float4*)(src + i) : make_float4(0.f, 0.f, 0.f, 0.f);
    __hip_bfloat162 p0, p1;
    p0.x = __float2bfloat16(v.x); p0.y = __float2bfloat16(v.y);
    p1.x = __float2bfloat16(v.z); p1.y = __float2bfloat16(v.w);
    *(__hip_bfloat162*)(dst + i) = p0;
    *(__hip_bfloat162*)(dst + i + 2) = p1;
}

// ---------------- Kernel 2: GEMM1 256m x 128j, BK=32, two-phase dbuf ----------------
// 512 thr / 8 waves. LDS 48 KB = 2buf x (A 128x32 + B 256x32) bf16.
// STAGE(next) issued BEFORE compute; single vmcnt(0)+barrier per K-step (T3-min).
// Swizzle: LDS[row][c] = G[row][c ^ (row&3)] (16B chunks); read pch = ((lane>>4)^(lane&3))*8.
// T1: 1120 blocks = 8 XCD x (35 j outer x 4 m inner).
__global__ __launch_bounds__(512, 4) void gemm1_mfma256(const __hip_bfloat16* __restrict__ Wb,
                                                        const __hip_bfloat16* __restrict__ xn,
                                                        short* __restrict__ zx) {
    __shared__ short As[2][128][32];
    __shared__ short Bs[2][256][32];
    int tid = threadIdx.x;
    int lane = tid & 63;
    int wave = tid >> 6;           // 0..7
    int wm = wave >> 1;            // m-quarter (64 m)
    int wn = wave & 1;             // j-half (64 j)
    int id = blockIdx.x;
    int xcd = id & 7;
    int pos = id >> 3;             // [0, 140)
    int j0 = (pos >> 2) * 128;     // j outer: 35 panels
    int m0 = (xcd * 4 + (pos & 3)) * 256;   // m inner: strip L2-resident
    int arow = wave * 16 + (lane >> 2);     // staging row within a 128-row round
    int skc = (((lane & 3) ^ ((lane >> 2) & 3)) * 8);  // pre-swizzled source k-offset

    f32x4 acc[4][4] = {};

    // prologue: stage K-tile 0 into buf 0
    gload16(Wb + (size_t)(j0 + arow) * DM + skc, ((short*)As) + wave * 512);
    gload16(xn + (size_t)(m0 + arow) * DM + skc, ((short*)Bs) + wave * 512);
    gload16(xn + (size_t)(m0 + 128 + arow) * DM + skc, ((short*)Bs) + 4096 + wave * 512);
    asm volatile("s_waitcnt vmcnt(0)" ::: "memory");
    __syncthreads();

    int buf = 0;
    for (int kt = 0; kt < 32; kt++) {
        if (kt < 31) {
            int k0 = (kt + 1) * 32;
            int ob = buf ^ 1;
            gload16(Wb + (size_t)(j0 + arow) * DM + k0 + skc,
                    ((short*)As) + ob * 4096 + wave * 512);
            gload16(xn + (size_t)(m0 + arow) * DM + k0 + skc,
                    ((short*)Bs) + ob * 8192 + wave * 512);
            gload16(xn + (size_t)(m0 + 128 + arow) * DM + k0 + skc,
                    ((short*)Bs) + ob * 8192 + 4096 + wave * 512);
        }
        int pch = ((lane >> 4) ^ (lane & 3)) * 8;
        bf16x8 af[4], bfr[4];
#pragma unroll
        for (int i = 0; i < 4; i++)
            af[i] = *(const bf16x8*)&As[buf][wn * 64 + i * 16 + (lane & 15)][pch];
#pragma unroll
        for (int n = 0; n < 4; n++)
            bfr[n] = *(const bf16x8*)&Bs[buf][wm * 64 + n * 16 + (lane & 15)][pch];
#pragma unroll
        for (int i = 0; i < 4; i++)
#pragma unroll
            for (int n = 0; n < 4; n++)
                acc[i][n] = __builtin_amdgcn_mfma_f32_16x16x32_bf16(af[i], bfr[n], acc[i][n], 0, 0, 0);
        asm volatile("s_waitcnt vmcnt(0)" ::: "memory");
        __syncthreads();
        buf ^= 1;
    }
#pragma unroll
    for (int i = 0; i < 4; i++) {
        int j = j0 + wn * 64 + i * 16 + ((lane >> 4) << 2);
        if (j < DIP) {
#pragma unroll
            for (int n = 0; n < 4; n++) {
                int m = m0 + wm * 64 + n * 16 + (lane & 15);
                short4 s4;
                s4.x = f2bs(acc[i][n][0]); s4.y = f2bs(acc[i][n][1]);
                s4.z = f2bs(acc[i][n][2]); s4.w = f2bs(acc[i][n][3]);
                *(short4*)(zx + (size_t)m * DIP + j) = s4;
            }
        }
    }
}

// ---------------- Kernel 2b: split-K f32 strip GEMM for dt cols -> partial sums ----------------
__global__ __launch_bounds__(256) void gemm1_strip(const float* __restrict__ x,
                                                   const float* __restrict__ mu,
                                                   const float* __restrict__ rs,
                                                   const float* __restrict__ ln_w,
                                                   const float* __restrict__ ln_b,
                                                   const float* __restrict__ Win,
                                                   float* __restrict__ partial) {
    __shared__ float As[16][64];
    __shared__ float Ws[64][17];
    int tid = threadIdx.x;
    int tx = tid & 15;
    int ty = tid >> 4;
    int j0 = 4352;
    int kq = blockIdx.x;
    int m0 = blockIdx.y * 64;
    int b = m0 >> 12;
    int t0 = m0 & 4095;
    const float* Xb = x + (size_t)b * DM * TT + t0;

    int lr = tid >> 4;
    int lc = (tid & 15) * 4;
    int wr = tid >> 2;
    int wc = (tid & 3) * 4;

    float acc[4][4] = {};
    int kbeg = kq * (DM / KSPLIT);
    for (int k0 = kbeg; k0 < kbeg + DM / KSPLIT; k0 += 16) {
        float4 xv = *(const float4*)(Xb + (size_t)(k0 + lr) * TT + lc);
        float4 muv = *(const float4*)(&mu[m0 + lc]);
        float4 rsv = *(const float4*)(&rs[m0 + lc]);
        float lw = ln_w[k0 + lr], lb = ln_b[k0 + lr];
        As[lr][lc]     = (xv.x - muv.x) * rsv.x * lw + lb;
        As[lr][lc + 1] = (xv.y - muv.y) * rsv.y * lw + lb;
        As[lr][lc + 2] = (xv.z - muv.z) * rsv.z * lw + lb;
        As[lr][lc + 3] = (xv.w - muv.w) * rsv.w * lw + lb;

        int j = j0 + wr;
        float4 wv = make_float4(0.f, 0.f, 0.f, 0.f);
        if (j < DIP) wv = *(const float4*)(Win + (size_t)j * DM + k0 + wc);
        Ws[wr][wc] = wv.x; Ws[wr][wc + 1] = wv.y; Ws[wr][wc + 2] = wv.z; Ws[wr][wc + 3] = wv.w;
        __syncthreads();
#pragma unroll
        for (int kk = 0; kk < 16; kk++) {
            float4 a4 = *(const float4*)&As[kk][ty * 4];
            float a[4] = {a4.x, a4.y, a4.z, a4.w};
            float bv[4];
#pragma unroll
            for (int n = 0; n < 4; n++) bv[n] = Ws[tx * 4 + n][kk];
#pragma unroll
            for (int i = 0; i < 4; i++)
#pragma unroll
                for (int n = 0; n < 4; n++)
                    acc[i][n] = fmaf(a[i], bv[n], acc[i][n]);
        }
        __syncthreads();
    }
#pragma unroll
    for (int i = 0; i < 4; i++) {
        int m = m0 + ty * 4 + i;
        int hh = tx * 4;
        if (hh < NH) {
            float4 v = make_float4(acc[i][0], acc[i][1], acc[i][2], acc[i][3]);
            *(float4*)(partial + ((size_t)kq * BB * TT + m) * NH + hh) = v;
        }
    }
}

// ---------------- Kernel 2c: reduce split-K partials + bias + softplus -> dtv ----------------
__global__ __launch_bounds__(256) void dt_reduce_kernel(const float* __restrict__ partial,
                                                        const float* __restrict__ dt_bias,
                                                        float* __restrict__ dtv) {
    int i = blockIdx.x * 256 + threadIdx.x;
    int hh = i & (NH - 1);
    float s = 0.f;
#pragma unroll
    for (int kq = 0; kq < KSPLIT; kq++)
        s += partial[(size_t)kq * BB * TT * NH + i];
    float raw = s + dt_bias[hh];
    dtv[i] = (raw > 20.f) ? raw : log1pf(expf(raw));
}

// ---------------- Kernel 3: causal depthwise conv(4) + SiLU — 4t x 8ch register reuse ----------------
__global__ __launch_bounds__(256) void conv_kernel(const short* __restrict__ zx,
                                                   const float* __restrict__ cw,
                                                   const float* __restrict__ cb,
                                                   short* __restrict__ xBC) {
    int gid = blockIdx.x * 256 + threadIdx.x;      // over BB*(TT/4)*(CD/8)
    int cq = gid % (CD / 8);
    int tq = (gid / (CD / 8)) % (TT / 4);
    int b  = gid / ((CD / 8) * (TT / 4));
    int c = cq * 8, tb = tq * 4;
    const short* src = zx + (size_t)b * TT * DIP + DI + c;

    float wv[8][4];
    float acc[4][8];
#pragma unroll
    for (int e = 0; e < 8; e++) {
        float4 w4 = *(const float4*)(cw + (c + e) * 4);
        wv[e][0] = w4.x; wv[e][1] = w4.y; wv[e][2] = w4.z; wv[e][3] = w4.w;
        float bias = cb[c + e];
#pragma unroll
        for (int o = 0; o < 4; o++) acc[o][e] = bias;
    }

#pragma unroll
    for (int r = 0; r < 7; r++) {
        int ts = tb - 3 + r;
        if (ts >= 0) {
            bf16x8 v = *(const bf16x8*)(src + (size_t)ts * DIP);
            float rowf[8];
#pragma unroll
            for (int e = 0; e < 8; e++) rowf[e] = b2f(v[e]);
#pragma unroll
            for (int o = 0; o < 4; o++) {
                if (o <= r && r <= o + 3) {
                    int k = r - o;
#pragma unroll
                    for (int e = 0; e < 8; e++)
                        acc[o][e] = fmaf(wv[e][k], rowf[e], acc[o][e]);
                }
            }
        }
    }
#pragma unroll
    for (int o = 0; o < 4; o++) {
        short out[8];
#pragma unroll
        for (int e = 0; e < 8; e++) {
            float sg = 1.f / (1.f + expf(-acc[o][e]));
            out[e] = f2bs(acc[o][e] * sg);
        }
        *(bf16x8*)(xBC + ((size_t)b * TT + tb + o) * CD + c) = *(bf16x8*)out;
    }
}

// ---------------- Kernel 5a: SSD chunk reduce (prefix fused into P0; 3 barriers/fc) ----------------
__global__ __launch_bounds__(256, 2) void scan_reduce_ssd(const short* __restrict__ xBC,
                                                          const float* __restrict__ dtg,
                                                          const float* __restrict__ A_log,
                                                          float* __restrict__ S,
                                                          float* __restrict__ P) {
    int tid = threadIdx.x;
    int wave = tid >> 6, lane = tid & 63;
    int l4 = lane >> 4, l16 = lane & 15;
    int c = blockIdx.x, hh = blockIdx.y, b = blockIdx.z;
    int cbase = c * CL;

    __shared__ __align__(16) short BtL[64][136];
    __shared__ __align__(16) short XdL[64][72];
    __shared__ __align__(16) float sdt[64];
    __shared__ __align__(16) float sL[64];
    __shared__ __align__(16) float sW[64];

    f32x4 acc_h[2][4];
#pragma unroll
    for (int i = 0; i < 2; i++)
#pragma unroll
        for (int pq = 0; pq < 4; pq++) acc_h[i][pq] = (f32x4){0.f, 0.f, 0.f, 0.f};
    float Lsum = 0.f;

    float expA = expf(A_log[hh]);
    const float* dtb = dtg + (size_t)b * TT * NH + hh;
    const short* xb = xBC + (size_t)b * TT * CD;

#pragma unroll 1
    for (int f = 0; f < FPC; f++) {
        int t0 = cbase + f * FL;
        if (tid < 64) {
            float val = dtb[(size_t)(t0 + tid) * NH];
            sdt[tid] = val;
            float v = -expA * val;
#pragma unroll
            for (int off = 1; off < 64; off <<= 1) {
                float u = __shfl_up(v, off);
                if (lane >= off) v += u;
            }
            sL[tid] = v;
            float lt = __shfl(v, 63);
            sW[tid] = expf(lt - v);
        }
        {
            int r = tid >> 2, q = tid & 3;
            const short* bs = xb + (size_t)(t0 + r) * CD + DI + q * 32;
#pragma unroll
            for (int j = 0; j < 4; j++)
                *(bf16x8*)&BtL[r][q * 32 + j * 8] = *(const bf16x8*)(bs + j * 8);
        }
        __syncthreads();
        {
            int s = tid & 63, pg2 = tid >> 6;
            const short* xs = xb + (size_t)(t0 + s) * CD + hh * HD + pg2 * 16;
            float dw = sdt[s] * sW[s];
            bf16x8 v0 = *(const bf16x8*)xs;
            bf16x8 v1 = *(const bf16x8*)(xs + 8);
#pragma unroll
            for (int j = 0; j < 8; j++) XdL[pg2 * 16 + j][s] = f2bs(b2f(v0[j]) * dw);
#pragma unroll
            for (int j = 0; j < 8; j++) XdL[pg2 * 16 + 8 + j][s] = f2bs(b2f(v1[j]) * dw);
        }
        __syncthreads();
        float Lft = sL[63];
        float Pf = expf(Lft);
        Lsum += Lft;
#pragma unroll
        for (int i = 0; i < 2; i++)
#pragma unroll
            for (int pq = 0; pq < 4; pq++) acc_h[i][pq] *= Pf;
#pragma unroll
        for (int ks = 0; ks < 2; ks++) {
            bf16x8 af2[2], bfw[4];
#pragma unroll
            for (int i = 0; i < 2; i++) {
                int nrow = wave * 32 + i * 16 + l16;
                short e[8];
#pragma unroll
                for (int j = 0; j < 8; j++)
                    e[j] = BtL[ks * 32 + l4 * 8 + j][nrow];
                af2[i] = *(bf16x8*)e;
            }
#pragma unroll
            for (int pq = 0; pq < 4; pq++)
                bfw[pq] = *(const bf16x8*)&XdL[pq * 16 + l16][ks * 32 + l4 * 8];
#pragma unroll
            for (int i = 0; i < 2; i++)
#pragma unroll
                for (int pq = 0; pq < 4; pq++)
                    acc_h[i][pq] = __builtin_amdgcn_mfma_f32_16x16x32_bf16(af2[i], bfw[pq], acc_h[i][pq], 0, 0, 0);
        }
        __syncthreads();
    }

    float* Sp = S + (size_t)c * SELEMS + ((size_t)(b * NH + hh) * HD) * DSTATE;
#pragma unroll
    for (int i = 0; i < 2; i++)
#pragma unroll
        for (int pq = 0; pq < 4; pq++) {
            int nb = wave * 32 + i * 16 + (l4 << 2);
            int p = pq * 16 + l16;
            *(f32x4*)(Sp + (size_t)p * DSTATE + nb) = acc_h[i][pq];
        }
    if (tid == 0) P[(c * BB + b) * NH + hh] = expf(Lsum);
}

// ---------------- Kernel 5b: sequential chunk combine ----------------
__global__ __launch_bounds__(256) void scan_combine_kernel(const float* __restrict__ h0,
                                                           const float* __restrict__ P,
                                                           float* __restrict__ S,
                                                           float* __restrict__ hT) {
    size_t tid = (size_t)blockIdx.x * 256 + threadIdx.x;
    int hh = (int)((tid >> 13) & 31);
    int b = (int)(tid >> 18);
    float h = h0[tid];
#pragma unroll
    for (int c = 0; c < NC; c++) {
        float s = S[(size_t)c * SELEMS + tid];
        S[(size_t)c * SELEMS + tid] = h;
        h = fmaf(P[(c * BB + b) * NH + hh], h, s);
    }
    hT[tid] = h;
}

// ---------------- Kernel 5c: SSD emit (prefix fused into P0; 4 barriers/fc) ----------------
__global__ __launch_bounds__(256, 2) void scan_emit_ssd(const short* __restrict__ xBC,
                                                        const float* __restrict__ dtg,
                                                        const float* __restrict__ A_log,
                                                        const float* __restrict__ S,
                                                        const float* __restrict__ Dp,
                                                        short* __restrict__ ybq) {
    int tid = threadIdx.x;
    int wave = tid >> 6, lane = tid & 63;
    int l4 = lane >> 4, l16 = lane & 15;
    int c = blockIdx.x, hh = blockIdx.y, b = blockIdx.z;
    int cbase = c * CL;

    __shared__ __align__(16) short CtL[64][136];
    __shared__ __align__(16) short BtL[64][136];
    __shared__ __align__(16) short hL[64][132];
    __shared__ __align__(16) short XdL[64][72];
    __shared__ __align__(16) short XdwL[64][72];
    __shared__ __align__(16) short ML[64][72];
    __shared__ __align__(16) float sdt[64];
    __shared__ __align__(16) float sL[64];
    __shared__ __align__(16) float sW[64];
    __shared__ __align__(16) float sRdt[64];

    f32x4 acc_h[2][4];
    {
        const float* Sp = S + (size_t)c * SELEMS + ((size_t)(b * NH + hh) * HD) * DSTATE;
#pragma unroll
        for (int i = 0; i < 2; i++)
#pragma unroll
            for (int pq = 0; pq < 4; pq++) {
                int nb = wave * 32 + i * 16 + (l4 << 2);
                int p = pq * 16 + l16;
                acc_h[i][pq] = *(const f32x4*)(Sp + (size_t)p * DSTATE + nb);
            }
    }

    float expA = expf(A_log[hh]);
    float Dh = Dp[hh];
    const float* dtb = dtg + (size_t)b * TT * NH + hh;
    const short* xb = xBC + (size_t)b * TT * CD;
    short* yb = ybq + (size_t)b * TT * DI + hh * HD;

    int tg = wave >> 1;
    int sg = wave & 1;

#pragma unroll 1
    for (int f = 0; f < FPC; f++) {
        int t0 = cbase + f * FL;

        if (tid < 64) {
            float val = dtb[(size_t)(t0 + tid) * NH];
            sdt[tid] = val;
            float v = -expA * val;
#pragma unroll
            for (int off = 1; off < 64; off <<= 1) {
                float u = __shfl_up(v, off);
                if (lane >= off) v += u;
            }
            sL[tid] = v;
            float lt = __shfl(v, 63);
            sW[tid] = expf(lt - v);
            sRdt[tid] = 1.f / val;
        }
        {
            int r = tid >> 2, q = tid & 3;
            const short* cs = xb + (size_t)(t0 + r) * CD + DI + DSTATE + q * 32;
            const short* bs = xb + (size_t)(t0 + r) * CD + DI + q * 32;
#pragma unroll
            for (int j = 0; j < 4; j++) {
                *(bf16x8*)&CtL[r][q * 32 + j * 8] = *(const bf16x8*)(cs + j * 8);
                *(bf16x8*)&BtL[r][q * 32 + j * 8] = *(const bf16x8*)(bs + j * 8);
            }
        }
#pragma unroll
        for (int i = 0; i < 2; i++)
#pragma unroll
            for (int pq = 0; pq < 4; pq++) {
                int nb = wave * 32 + i * 16 + (l4 << 2);
                int p = pq * 16 + l16;
                *(short2*)&hL[p][nb] = make_short2(f2bs(acc_h[i][pq][0]), f2bs(acc_h[i][pq][1]));
                *(short2*)&hL[p][nb + 2] = make_short2(f2bs(acc_h[i][pq][2]), f2bs(acc_h[i][pq][3]));
            }
        __syncthreads();

        {
            int s = tid & 63, pg = tid >> 6;
            const short* xs = xb + (size_t)(t0 + s) * CD + hh * HD + pg * 16;
            float dts = sdt[s];
            float dw = dts * sW[s];
            bf16x8 v0 = *(const bf16x8*)xs;
            bf16x8 v1 = *(const bf16x8*)(xs + 8);
#pragma unroll
            for (int j = 0; j < 8; j++) {
                float xv = b2f(v0[j]);
                XdL[pg * 16 + j][s] = f2bs(xv * dts);
                XdwL[pg * 16 + j][s] = f2bs(xv * dw);
            }
#pragma unroll
            for (int j = 0; j < 8; j++) {
                float xv = b2f(v1[j]);
                XdL[pg * 16 + 8 + j][s] = f2bs(xv * dts);
                XdwL[pg * 16 + 8 + j][s] = f2bs(xv * dw);
            }
        }
        __syncthreads();

        {
            f32x4 g[2][2] = {};
#pragma unroll
            for (int ks = 0; ks < 4; ks++) {
                bf16x8 af[2], bfm[2];
#pragma unroll
                for (int i = 0; i < 2; i++)
                    af[i] = *(const bf16x8*)&CtL[tg * 32 + i * 16 + l16][ks * 32 + l4 * 8];
#pragma unroll
                for (int n = 0; n < 2; n++)
                    bfm[n] = *(const bf16x8*)&BtL[sg * 32 + n * 16 + l16][ks * 32 + l4 * 8];
#pragma unroll
                for (int i = 0; i < 2; i++)
#pragma unroll
                    for (int n = 0; n < 2; n++)
                        g[i][n] = __builtin_amdgcn_mfma_f32_16x16x32_bf16(af[i], bfm[n], g[i][n], 0, 0, 0);
            }
#pragma unroll
            for (int i = 0; i < 2; i++) {
                int tb2 = tg * 32 + i * 16 + (l4 << 2);
                float4 Lt = *(const float4*)&sL[tb2];
                float Ltr[4] = {Lt.x, Lt.y, Lt.z, Lt.w};
#pragma unroll
                for (int n = 0; n < 2; n++) {
                    int sE = sg * 32 + n * 16 + l16;
                    float Ls = sL[sE];
#pragma unroll
                    for (int r2 = 0; r2 < 4; r2++) {
                        float m = (sE <= tb2 + r2) ? g[i][n][r2] * expf(Ltr[r2] - Ls) : 0.f;
                        ML[tb2 + r2][sE] = f2bs(m);
                    }
                }
            }
        }
        __syncthreads();

        {
            f32x4 ay[2][2] = {};
            f32x4 ai[2][2] = {};
#pragma unroll
            for (int ks = 0; ks < 2; ks++) {
                bf16x8 af[2], bfp[2];
#pragma unroll
                for (int i = 0; i < 2; i++)
                    af[i] = *(const bf16x8*)&ML[tg * 32 + i * 16 + l16][ks * 32 + l4 * 8];
#pragma unroll
                for (int n = 0; n < 2; n++)
                    bfp[n] = *(const bf16x8*)&XdL[sg * 32 + n * 16 + l16][ks * 32 + l4 * 8];
#pragma unroll
                for (int i = 0; i < 2; i++)
#pragma unroll
                    for (int n = 0; n < 2; n++)
                        ay[i][n] = __builtin_amdgcn_mfma_f32_16x16x32_bf16(af[i], bfp[n], ay[i][n], 0, 0, 0);
            }
#pragma unroll
            for (int ks = 0; ks < 4; ks++) {
                bf16x8 af[2], bfh[2];
#pragma unroll
                for (int i = 0; i < 2; i++)
                    af[i] = *(const bf16x8*)&CtL[tg * 32 + i * 16 + l16][ks * 32 + l4 * 8];
#pragma unroll
                for (int n = 0; n < 2; n++) {
                    int prow = sg * 32 + n * 16 + l16;
                    int kb = ks * 32 + l4 * 8;
                    union { bf16x8 v; uint2 u2[2]; } hu;
                    hu.u2[0] = *(const uint2*)&hL[prow][kb];
                    hu.u2[1] = *(const uint2*)&hL[prow][kb + 4];
                    bfh[n] = hu.v;
                }
#pragma unroll
                for (int i = 0; i < 2; i++)
#pragma unroll
                    for (int n = 0; n < 2; n++)
                        ai[i][n] = __builtin_amdgcn_mfma_f32_16x16x32_bf16(af[i], bfh[n], ai[i][n], 0, 0, 0);
            }
            float Lft = sL[63];
#pragma unroll
            for (int i = 0; i < 2; i++) {
                int tb2 = tg * 32 + i * 16 + (l4 << 2);
                float4 Lt = *(const float4*)&sL[tb2];
                float4 Rt = *(const float4*)&sRdt[tb2];
                float Ltr[4] = {Lt.x, Lt.y, Lt.z, Lt.w};
                float Rtr[4] = {Rt.x, Rt.y, Rt.z, Rt.w};
#pragma unroll
                for (int n = 0; n < 2; n++) {
                    int p = sg * 32 + n * 16 + l16;
#pragma unroll
                    for (int r2 = 0; r2 < 4; r2++) {
                        float xv = b2f(XdL[p][tb2 + r2]) * Rtr[r2];
                        float yv = ay[i][n][r2] + expf(Ltr[r2]) * ai[i][n][r2] + Dh * xv;
                        yb[(size_t)(t0 + tb2 + r2) * DI + p] = f2bs(yv);
                    }
                }
            }
            float Pf = expf(Lft);
#pragma unroll
            for (int i = 0; i < 2; i++)
#pragma unroll
                for (int pq = 0; pq < 4; pq++)
                    acc_h[i][pq] *= Pf;
#pragma unroll
            for (int ks = 0; ks < 2; ks++) {
                bf16x8 af2[2], bfw[4];
#pragma unroll
                for (int i = 0; i < 2; i++) {
                    int nrow = wave * 32 + i * 16 + l16;
                    short e[8];
#pragma unroll
                    for (int j = 0; j < 8; j++)
                        e[j] = BtL[ks * 32 + l4 * 8 + j][nrow];
                    af2[i] = *(bf16x8*)e;
                }
#pragma unroll
                for (int pq = 0; pq < 4; pq++)
                    bfw[pq] = *(const bf16x8*)&XdwL[pq * 16 + l16][ks * 32 + l4 * 8];
#pragma unroll
                for (int i = 0; i < 2; i++)
#pragma unroll
                    for (int pq = 0; pq < 4; pq++)
                        acc_h[i][pq] = __builtin_amdgcn_mfma_f32_16x16x32_bf16(af2[i], bfw[pq], acc_h[i][pq], 0, 0, 0);
            }
        }
        __syncthreads();
    }
}

// ---------------- Kernel 6: gating + RMSNorm (bf16 y, bf16 z) -> bf16 g ----------------
__global__ __launch_bounds__(256) void gate_rms_kernel(const short* __restrict__ ybq,
                                                       const short* __restrict__ zx,
                                                       const float* __restrict__ rw,
                                                       __hip_bfloat16* __restrict__ gq) {
    int m = blockIdx.x;
    int tid = threadIdx.x;
    const short* yr = ybq + (size_t)m * DI;
    const short* zr = zx + (size_t)m * DIP;
    int base = tid * 8;
    float gv[8];
    float ss = 0.f;
    bf16x8 yv8 = *(const bf16x8*)(yr + base);
    bf16x8 zv8 = *(const bf16x8*)(zr + base);
#pragma unroll
    for (int i = 0; i < 8; i++) {
        float y = b2f(yv8[i]);
        float z = b2f(zv8[i]);
        float sg = 1.f / (1.f + expf(-z));
        float gg = y * z * sg;
        gv[i] = gg;
        ss += gg * gg;
    }
#pragma unroll
    for (int off = 1; off < 64; off <<= 1) ss += __shfl_xor(ss, off);
    __shared__ float red[4];
    int w = tid >> 6;
    if ((tid & 63) == 0) red[w] = ss;
    __syncthreads();
    float tot = red[0] + red[1] + red[2] + red[3];
    float r = rsqrtf(tot * (1.f / DI) + 1e-5f);
#pragma unroll
    for (int i = 0; i < 8; i += 2) {
        __hip_bfloat162 p;
        p.x = __float2bfloat16(gv[i] * r * rw[base + i]);
        p.y = __float2bfloat16(gv[i + 1] * r * rw[base + i + 1]);
        *(__hip_bfloat162*)(gq + (size_t)m * DI + base + i) = p;
    }
}

// ---------------- Kernel 7: GEMM2 bf16 MFMA (T2 swizzle + T1 remap m-inner, transposed store) ----------------
__global__ __launch_bounds__(256) void gemm2_mfma(const __hip_bfloat16* __restrict__ gq,
                                                  const __hip_bfloat16* __restrict__ Wob,
                                                  float* __restrict__ out) {
    __shared__ short As[128][64];
    __shared__ short Bs[128][64];
    int tid = threadIdx.x;
    int lane = tid & 63;
    int wave = tid >> 6;
    int wr = wave >> 1, wc = wave & 1;
    int id = blockIdx.x;
    int xcd = id & 7;
    int pos = id >> 3;
    int j0 = (pos >> 3) * 128;
    int m0 = (xcd * 8 + (pos & 7)) * 128;
    int srow = tid >> 3;
    int skc = (((tid & 7) ^ ((tid >> 3) & 7)) * 8);

    f32x4 acc[4][4] = {};

    for (int k0 = 0; k0 < DI; k0 += 64) {
        __syncthreads();
#pragma unroll
        for (int q = 0; q < 4; q++) {
            gload16(gq + (size_t)(m0 + q * 32 + srow) * DI + k0 + skc,
                    ((short*)As) + q * 2048 + wave * 512);
            gload16(Wob + (size_t)(j0 + q * 32 + srow) * DI + k0 + skc,
                    ((short*)Bs) + q * 2048 + wave * 512);
        }
        asm volatile("s_waitcnt vmcnt(0)" ::: "memory");
        __syncthreads();
#pragma unroll
        for (int ks = 0; ks < 2; ks++) {
            int pch = (((ks * 4) + (lane >> 4)) ^ (lane & 7)) * 8;
            bf16x8 af[4], bfr[4];
#pragma unroll
            for (int i = 0; i < 4; i++)
                af[i] = *(const bf16x8*)&As[wr * 64 + i * 16 + (lane & 15)][pch];
#pragma unroll
            for (int n = 0; n < 4; n++)
                bfr[n] = *(const bf16x8*)&Bs[wc * 64 + n * 16 + (lane & 15)][pch];
#pragma unroll
            for (int i = 0; i < 4; i++)
#pragma unroll
                for (int n = 0; n < 4; n++)
                    acc[i][n] = __builtin_amdgcn_mfma_f32_16x16x32_bf16(af[i], bfr[n], acc[i][n], 0, 0, 0);
        }
    }
#pragma unroll
    for (int i = 0; i < 4; i++) {
        int m = m0 + wr * 64 + i * 16 + ((lane >> 4) << 2);
        int b = m >> 12;
        int t = m & 4095;
#pragma unroll
        for (int n = 0; n < 4; n++) {
            int j = j0 + wc * 64 + n * 16 + (lane & 15);
            *(f32x4*)(out + (size_t)b * DM * TT + (size_t)j * TT + t) = acc[i][n];
        }
    }
}

extern "C" void kernel_launch(void* const* d_in, const int* in_sizes, int n_in,
                              void* d_out, int out_size, void* d_ws, size_t ws_size,
                              hipStream_t stream) {
    const float* x       = (const float*)d_in[0];
    const float* ln_w    = (const float*)d_in[1];
    const float* ln_b    = (const float*)d_in[2];
    const float* W_in    = (const float*)d_in[3];
    const float* conv_w  = (const float*)d_in[4];
    const float* conv_b  = (const float*)d_in[5];
    const float* dt_bias = (const float*)d_in[6];
    const float* A_log   = (const float*)d_in[7];
    const float* Dp      = (const float*)d_in[8];
    const float* rms_w   = (const float*)d_in[9];
    const float* W_out   = (const float*)d_in[10];
    const float* h0      = (const float*)d_in[11];

    float* out = (float*)d_out;
    float* hT = out + (size_t)BB * DM * TT;

    char* ws = (char*)d_ws;
    // Workspace layout — total 211,355,648 bytes:
    float* mu   = (float*)(ws + 0);
    float* rs   = (float*)(ws + 32768);
    short* zxq  = (short*)(ws + 65536);                   //  71,827,456  (B,T,4384) bf16
    short* xBCq = (short*)(ws + 71892992);                //  37,748,736  (B,T,2304) bf16
    __hip_bfloat16* gq  = (__hip_bfloat16*)(ws + 71892992);
    __hip_bfloat16* Wob = (__hip_bfloat16*)(ws + 105447424);
    short* ybq  = (short*)(ws + 109641728);               //  33,554,432  (B,T,2048) bf16
    __hip_bfloat16* Wb  = (__hip_bfloat16*)(ws + 109641728);
    float* dtv  = (float*)(ws + 176750592);
    __hip_bfloat16* xnb = (__hip_bfloat16*)(ws + 177799168);
    float* S    = (float*)(ws + 177799168);
    float* P    = (float*)(ws + 194576384);
    float* dpart = (float*)(ws + 194578432);              //  16,777,216

    ln_stats_kernel<<<(TT / 32) * BB, 256, 0, stream>>>(x, mu, rs);
    xn_kernel<<<dim3(TT / 64, DM / 64, BB), 256, 0, stream>>>(x, mu, rs, ln_w, ln_b, xnb);
    cvt_pad_kernel<<<(NP1 * DM) / 1024, 256, 0, stream>>>(W_in, Wb, DIP * DM, NP1 * DM);
    gemm1_mfma256<<<(NP1 / 128) * ((BB * TT) / 256), 512, 0, stream>>>(Wb, xnb, zxq);
    gemm1_strip<<<dim3(KSPLIT, (BB * TT) / 64), 256, 0, stream>>>(x, mu, rs, ln_w, ln_b, W_in, dpart);
    dt_reduce_kernel<<<(BB * TT * NH) / 256, 256, 0, stream>>>(dpart, dt_bias, dtv);
    conv_kernel<<<(BB * (TT / 4) * (CD / 8)) / 256, 256, 0, stream>>>(zxq, conv_w, conv_b, xBCq);
    scan_reduce_ssd<<<dim3(NC, NH, BB), 256, 0, stream>>>(xBCq, dtv, A_log, S, P);
    scan_combine_kernel<<<(int)(SELEMS / 256), 256, 0, stream>>>(h0, P, S, hT);
    scan_emit_ssd<<<dim3(NC, NH, BB), 256, 0, stream>>>(xBCq, dtv, A_log, S, Dp, ybq);
    cvt_pad_kernel<<<(DM * DI) / 1024, 256, 0, stream>>>(W_out, Wob, DM * DI, DM * DI);
    gate_rms_kernel<<<BB * TT, 256, 0, stream>>>(ybq, zxq, rms_w, gq);
    gemm2_mfma<<<((BB * TT) / 128) * (DM / 128), 256, 0, stream>>>(gq, Wob, out);
}

// Round 18
// 331.935 us; speedup vs baseline: 1.0095x; 1.0095x over previous
//
#include <hip/hip_runtime.h>
#include <hip/hip_bf16.h>
#include <math.h>

// Problem constants
#define BB 2
#define TT 4096
#define DM 1024
#define DSTATE 128
#define DI 2048
#define HD 64
#define NH 32
#define DIP 4384   // 2*DI + 2*DSTATE + NH
#define CD 2304    // DI + 2*DSTATE

// Chunked scan parameters
#define NC 8
#define CL 512
#define FL 64            // SSD fine-chunk length
#define FPC (CL / FL)    // 8
#define SELEMS ((size_t)BB * NH * HD * DSTATE)   // 524288

#define NP1 4480   // DIP padded to multiple of 128 for MFMA staging
#define KSPLIT 16  // split-K factor for the dt strip GEMM

typedef __attribute__((ext_vector_type(8))) short bf16x8;
typedef __attribute__((ext_vector_type(4))) float f32x4;

__device__ inline void gload16(const void* g, void* l) {
    __builtin_amdgcn_global_load_lds(
        (const __attribute__((address_space(1))) void*)g,
        (__attribute__((address_space(3))) void*)l, 16, 0, 0);
}

__device__ inline short f2bs(float f) {
    __hip_bfloat16 h = __float2bfloat16(f);
    union { __hip_bfloat16 h; short s; } u;
    u.h = h;
    return u.s;
}
__device__ inline float b2f(short s) {
    union { float f; unsigned u; } u;
    u.u = ((unsigned)(unsigned short)s) << 16;
    return u.f;
}

// ---------------- Kernel 1: LayerNorm statistics (split-D, 256 blocks) ----------------
__global__ __launch_bounds__(256) void ln_stats_kernel(const float* __restrict__ x,
                                                       float* __restrict__ mu,
                                                       float* __restrict__ rs) {
    __shared__ float sred[2][8][32];
    int tid = threadIdx.x;
    int tl = tid & 31;
    int ds = tid >> 5;               // 0..7
    int t = (blockIdx.x & 127) * 32 + tl;
    int b = blockIdx.x >> 7;
    const float* xb = x + (size_t)b * DM * TT + (size_t)ds * 128 * TT + t;
    float s = 0.f, ss = 0.f;
#pragma unroll 8
    for (int d = 0; d < 128; d++) {
        float v = xb[(size_t)d * TT];
        s += v;
        ss += v * v;
    }
    sred[0][ds][tl] = s;
    sred[1][ds][tl] = ss;
    __syncthreads();
    if (tid < 32) {
        float st = 0.f, sst = 0.f;
#pragma unroll
        for (int q = 0; q < 8; q++) { st += sred[0][q][tid]; sst += sred[1][q][tid]; }
        float m = st * (1.f / DM);
        float var = sst * (1.f / DM) - m * m;
        int idx = b * TT + (blockIdx.x & 127) * 32 + tid;
        mu[idx] = m;
        rs[idx] = rsqrtf(var + 1e-5f);
    }
}

// ---------------- Kernel 1b: xn = LN(x) transposed to (m, k) in bf16 ----------------
__global__ __launch_bounds__(256) void xn_kernel(const float* __restrict__ x,
                                                 const float* __restrict__ mu,
                                                 const float* __restrict__ rs,
                                                 const float* __restrict__ ln_w,
                                                 const float* __restrict__ ln_b,
                                                 __hip_bfloat16* __restrict__ xn) {
    __shared__ float tile[64][65];
    int tid = threadIdx.x;
    int t0 = blockIdx.x * 64, d0 = blockIdx.y * 64, b = blockIdx.z;
#pragma unroll
    for (int i = 0; i < 64; i += 4) {
        int dl = i + (tid >> 6);
        tile[dl][tid & 63] = x[(size_t)b * DM * TT + (size_t)(d0 + dl) * TT + t0 + (tid & 63)];
    }
    __syncthreads();
#pragma unroll
    for (int i = 0; i < 64; i += 8) {
        int tl = i + (tid >> 5);
        int kk = (tid & 31) * 2;
        int m = b * TT + t0 + tl;
        float mu_m = mu[m], rs_m = rs[m];
        float v0 = (tile[kk][tl] - mu_m) * rs_m * ln_w[d0 + kk] + ln_b[d0 + kk];
        float v1 = (tile[kk + 1][tl] - mu_m) * rs_m * ln_w[d0 + kk + 1] + ln_b[d0 + kk + 1];
        __hip_bfloat162 pk;
        pk.x = __float2bfloat16(v0);
        pk.y = __float2bfloat16(v1);
        *(__hip_bfloat162*)(xn + (size_t)m * DM + d0 + kk) = pk;
    }
}

// ---------------- convert f32 -> bf16 with zero-padding ----------------
__global__ __launch_bounds__(256) void cvt_pad_kernel(const float* __restrict__ src,
                                                      __hip_bfloat16* __restrict__ dst,
                                                      int src_n, int tot_n) {
    int i = (blockIdx.x * 256 + threadIdx.x) * 4;
    if (i >= tot_n) return;
    float4 v = (i < src_n) ? *(const float4*)(src + i) : make_float4(0.f, 0.f, 0.f, 0.f);
    __hip_bfloat162 p0, p1;
    p0.x = __float2bfloat16(v.x); p0.y = __float2bfloat16(v.y);
    p1.x = __float2bfloat16(v.z); p1.y = __float2bfloat16(v.w);
    *(__hip_bfloat162*)(dst + i) = p0;
    *(__hip_bfloat162*)(dst + i + 2) = p1;
}

// ---------------- Kernel 2: GEMM1 256m x 128j, BK=32, two-phase dbuf ----------------
// Paired-row 128B LDS lines: line L holds k-rows 2L,2L+1 (32 shorts each).
// Content cc = hi*4+kc stored at slot cc^(L&7); staging pre-swizzles the GLOBAL
// source per lane (LDS dest stays gload_lds-linear); reads apply the same XOR.
__global__ __launch_bounds__(512, 4) void gemm1_mfma256(const __hip_bfloat16* __restrict__ Wb,
                                                        const __hip_bfloat16* __restrict__ xn,
                                                        short* __restrict__ zx) {
    __shared__ short As[2][4096];   // 64 lines x 64 shorts per buf (128 j-rows)
    __shared__ short Bs[2][8192];   // 128 lines x 64 shorts per buf (256 m-rows)
    int tid = threadIdx.x;
    int lane = tid & 63;
    int wave = tid >> 6;           // 0..7
    int wm = wave >> 1;            // m-quarter (64 m)
    int wn = wave & 1;             // j-half (64 j)
    int id = blockIdx.x;
    int xcd = id & 7;
    int pos = id >> 3;             // [0, 140)
    int j0 = (pos >> 2) * 128;     // j outer: 35 panels
    int m0 = (xcd * 4 + (pos & 3)) * 256;   // m inner: strip L2-resident

    // staging decode: slot s=lane&7, Lrel=lane>>3, cc = s^Lrel -> (hi, kc)
    int sLrel = lane >> 3;
    int cc = (lane & 7) ^ sLrel;
    int hi = cc >> 2;
    int kcs = (cc & 3) * 8;                  // k offset in shorts
    int aRow = 2 * (wave * 8 + sLrel) + hi;  // A: j-row 0..127
    int bRow0 = 2 * (wave * 16 + sLrel) + hi;        // B call0: m-row
    int bRow1 = 2 * (wave * 16 + 8 + sLrel) + hi;    // B call1

    // read decode: ccr = (l&1)*4 + (l>>4), mask = (l>>1)&7, line base (l&15)>>1
    int rSlot = ((((lane & 1) << 2) + (lane >> 4)) ^ ((lane >> 1) & 7)) * 8;
    int rLb = (lane & 15) >> 1;

    f32x4 acc[4][4] = {};

    // prologue: stage K-tile 0 into buf 0
    gload16(Wb + (size_t)(j0 + aRow) * DM + kcs, As[0] + wave * 512);
    gload16(xn + (size_t)(m0 + bRow0) * DM + kcs, Bs[0] + wave * 1024);
    gload16(xn + (size_t)(m0 + bRow1) * DM + kcs, Bs[0] + wave * 1024 + 512);
    asm volatile("s_waitcnt vmcnt(0)" ::: "memory");
    __syncthreads();

    int buf = 0;
    for (int kt = 0; kt < 32; kt++) {
        if (kt < 31) {
            int k0 = (kt + 1) * 32;
            int ob = buf ^ 1;
            gload16(Wb + (size_t)(j0 + aRow) * DM + k0 + kcs, As[ob] + wave * 512);
            gload16(xn + (size_t)(m0 + bRow0) * DM + k0 + kcs, Bs[ob] + wave * 1024);
            gload16(xn + (size_t)(m0 + bRow1) * DM + k0 + kcs, Bs[ob] + wave * 1024 + 512);
        }
        bf16x8 af[4], bfr[4];
#pragma unroll
        for (int i = 0; i < 4; i++)
            af[i] = *(const bf16x8*)(As[buf] + (wn * 32 + i * 8 + rLb) * 64 + rSlot);
#pragma unroll
        for (int n = 0; n < 4; n++)
            bfr[n] = *(const bf16x8*)(Bs[buf] + (wm * 32 + n * 8 + rLb) * 64 + rSlot);
#pragma unroll
        for (int i = 0; i < 4; i++)
#pragma unroll
            for (int n = 0; n < 4; n++)
                acc[i][n] = __builtin_amdgcn_mfma_f32_16x16x32_bf16(af[i], bfr[n], acc[i][n], 0, 0, 0);
        asm volatile("s_waitcnt vmcnt(0)" ::: "memory");
        __syncthreads();
        buf ^= 1;
    }
#pragma unroll
    for (int i = 0; i < 4; i++) {
        int j = j0 + wn * 64 + i * 16 + ((lane >> 4) << 2);
        if (j < DIP) {
#pragma unroll
            for (int n = 0; n < 4; n++) {
                int m = m0 + wm * 64 + n * 16 + (lane & 15);
                short4 s4;
                s4.x = f2bs(acc[i][n][0]); s4.y = f2bs(acc[i][n][1]);
                s4.z = f2bs(acc[i][n][2]); s4.w = f2bs(acc[i][n][3]);
                *(short4*)(zx + (size_t)m * DIP + j) = s4;
            }
        }
    }
}

// ---------------- Kernel 2b: split-K f32 strip GEMM for dt cols -> partial sums ----------------
__global__ __launch_bounds__(256) void gemm1_strip(const float* __restrict__ x,
                                                   const float* __restrict__ mu,
                                                   const float* __restrict__ rs,
                                                   const float* __restrict__ ln_w,
                                                   const float* __restrict__ ln_b,
                                                   const float* __restrict__ Win,
                                                   float* __restrict__ partial) {
    __shared__ float As[16][64];
    __shared__ float Ws[64][17];
    int tid = threadIdx.x;
    int tx = tid & 15;
    int ty = tid >> 4;
    int j0 = 4352;
    int kq = blockIdx.x;
    int m0 = blockIdx.y * 64;
    int b = m0 >> 12;
    int t0 = m0 & 4095;
    const float* Xb = x + (size_t)b * DM * TT + t0;

    int lr = tid >> 4;
    int lc = (tid & 15) * 4;
    int wr = tid >> 2;
    int wc = (tid & 3) * 4;

    float acc[4][4] = {};
    int kbeg = kq * (DM / KSPLIT);
    for (int k0 = kbeg; k0 < kbeg + DM / KSPLIT; k0 += 16) {
        float4 xv = *(const float4*)(Xb + (size_t)(k0 + lr) * TT + lc);
        float4 muv = *(const float4*)(&mu[m0 + lc]);
        float4 rsv = *(const float4*)(&rs[m0 + lc]);
        float lw = ln_w[k0 + lr], lb = ln_b[k0 + lr];
        As[lr][lc]     = (xv.x - muv.x) * rsv.x * lw + lb;
        As[lr][lc + 1] = (xv.y - muv.y) * rsv.y * lw + lb;
        As[lr][lc + 2] = (xv.z - muv.z) * rsv.z * lw + lb;
        As[lr][lc + 3] = (xv.w - muv.w) * rsv.w * lw + lb;

        int j = j0 + wr;
        float4 wv = make_float4(0.f, 0.f, 0.f, 0.f);
        if (j < DIP) wv = *(const float4*)(Win + (size_t)j * DM + k0 + wc);
        Ws[wr][wc] = wv.x; Ws[wr][wc + 1] = wv.y; Ws[wr][wc + 2] = wv.z; Ws[wr][wc + 3] = wv.w;
        __syncthreads();
#pragma unroll
        for (int kk = 0; kk < 16; kk++) {
            float4 a4 = *(const float4*)&As[kk][ty * 4];
            float a[4] = {a4.x, a4.y, a4.z, a4.w};
            float bv[4];
#pragma unroll
            for (int n = 0; n < 4; n++) bv[n] = Ws[tx * 4 + n][kk];
#pragma unroll
            for (int i = 0; i < 4; i++)
#pragma unroll
                for (int n = 0; n < 4; n++)
                    acc[i][n] = fmaf(a[i], bv[n], acc[i][n]);
        }
        __syncthreads();
    }
#pragma unroll
    for (int i = 0; i < 4; i++) {
        int m = m0 + ty * 4 + i;
        int hh = tx * 4;
        if (hh < NH) {
            float4 v = make_float4(acc[i][0], acc[i][1], acc[i][2], acc[i][3]);
            *(float4*)(partial + ((size_t)kq * BB * TT + m) * NH + hh) = v;
        }
    }
}

// ---------------- Kernel 2c: reduce split-K partials + bias + softplus -> dtv ----------------
__global__ __launch_bounds__(256) void dt_reduce_kernel(const float* __restrict__ partial,
                                                        const float* __restrict__ dt_bias,
                                                        float* __restrict__ dtv) {
    int i = blockIdx.x * 256 + threadIdx.x;
    int hh = i & (NH - 1);
    float s = 0.f;
#pragma unroll
    for (int kq = 0; kq < KSPLIT; kq++)
        s += partial[(size_t)kq * BB * TT * NH + i];
    float raw = s + dt_bias[hh];
    dtv[i] = (raw > 20.f) ? raw : log1pf(expf(raw));
}

// ---------------- Kernel 3: causal depthwise conv(4) + SiLU — 4t x 8ch register reuse ----------------
__global__ __launch_bounds__(256) void conv_kernel(const short* __restrict__ zx,
                                                   const float* __restrict__ cw,
                                                   const float* __restrict__ cb,
                                                   short* __restrict__ xBC) {
    int gid = blockIdx.x * 256 + threadIdx.x;
    int cq = gid % (CD / 8);
    int tq = (gid / (CD / 8)) % (TT / 4);
    int b  = gid / ((CD / 8) * (TT / 4));
    int c = cq * 8, tb = tq * 4;
    const short* src = zx + (size_t)b * TT * DIP + DI + c;

    float wv[8][4];
    float acc[4][8];
#pragma unroll
    for (int e = 0; e < 8; e++) {
        float4 w4 = *(const float4*)(cw + (c + e) * 4);
        wv[e][0] = w4.x; wv[e][1] = w4.y; wv[e][2] = w4.z; wv[e][3] = w4.w;
        float bias = cb[c + e];
#pragma unroll
        for (int o = 0; o < 4; o++) acc[o][e] = bias;
    }

#pragma unroll
    for (int r = 0; r < 7; r++) {
        int ts = tb - 3 + r;
        if (ts >= 0) {
            bf16x8 v = *(const bf16x8*)(src + (size_t)ts * DIP);
            float rowf[8];
#pragma unroll
            for (int e = 0; e < 8; e++) rowf[e] = b2f(v[e]);
#pragma unroll
            for (int o = 0; o < 4; o++) {
                if (o <= r && r <= o + 3) {
                    int k = r - o;
#pragma unroll
                    for (int e = 0; e < 8; e++)
                        acc[o][e] = fmaf(wv[e][k], rowf[e], acc[o][e]);
                }
            }
        }
    }
#pragma unroll
    for (int o = 0; o < 4; o++) {
        short out[8];
#pragma unroll
        for (int e = 0; e < 8; e++) {
            float sg = 1.f / (1.f + expf(-acc[o][e]));
            out[e] = f2bs(acc[o][e] * sg);
        }
        *(bf16x8*)(xBC + ((size_t)b * TT + tb + o) * CD + c) = *(bf16x8*)out;
    }
}

// ---------------- Kernel 5a: SSD chunk reduce (prefix fused into P0; 3 barriers/fc) ----------------
__global__ __launch_bounds__(256, 2) void scan_reduce_ssd(const short* __restrict__ xBC,
                                                          const float* __restrict__ dtg,
                                                          const float* __restrict__ A_log,
                                                          float* __restrict__ S,
                                                          float* __restrict__ P) {
    int tid = threadIdx.x;
    int wave = tid >> 6, lane = tid & 63;
    int l4 = lane >> 4, l16 = lane & 15;
    int c = blockIdx.x, hh = blockIdx.y, b = blockIdx.z;
    int cbase = c * CL;

    __shared__ __align__(16) short BtL[64][136];
    __shared__ __align__(16) short XdL[64][72];
    __shared__ __align__(16) float sdt[64];
    __shared__ __align__(16) float sL[64];
    __shared__ __align__(16) float sW[64];

    f32x4 acc_h[2][4];
#pragma unroll
    for (int i = 0; i < 2; i++)
#pragma unroll
        for (int pq = 0; pq < 4; pq++) acc_h[i][pq] = (f32x4){0.f, 0.f, 0.f, 0.f};
    float Lsum = 0.f;

    float expA = expf(A_log[hh]);
    const float* dtb = dtg + (size_t)b * TT * NH + hh;
    const short* xb = xBC + (size_t)b * TT * CD;

#pragma unroll 1
    for (int f = 0; f < FPC; f++) {
        int t0 = cbase + f * FL;
        if (tid < 64) {
            float val = dtb[(size_t)(t0 + tid) * NH];
            sdt[tid] = val;
            float v = -expA * val;
#pragma unroll
            for (int off = 1; off < 64; off <<= 1) {
                float u = __shfl_up(v, off);
                if (lane >= off) v += u;
            }
            sL[tid] = v;
            float lt = __shfl(v, 63);
            sW[tid] = expf(lt - v);
        }
        {
            int r = tid >> 2, q = tid & 3;
            const short* bs = xb + (size_t)(t0 + r) * CD + DI + q * 32;
#pragma unroll
            for (int j = 0; j < 4; j++)
                *(bf16x8*)&BtL[r][q * 32 + j * 8] = *(const bf16x8*)(bs + j * 8);
        }
        __syncthreads();
        {
            int s = tid & 63, pg2 = tid >> 6;
            const short* xs = xb + (size_t)(t0 + s) * CD + hh * HD + pg2 * 16;
            float dw = sdt[s] * sW[s];
            bf16x8 v0 = *(const bf16x8*)xs;
            bf16x8 v1 = *(const bf16x8*)(xs + 8);
#pragma unroll
            for (int j = 0; j < 8; j++) XdL[pg2 * 16 + j][s] = f2bs(b2f(v0[j]) * dw);
#pragma unroll
            for (int j = 0; j < 8; j++) XdL[pg2 * 16 + 8 + j][s] = f2bs(b2f(v1[j]) * dw);
        }
        __syncthreads();
        float Lft = sL[63];
        float Pf = expf(Lft);
        Lsum += Lft;
#pragma unroll
        for (int i = 0; i < 2; i++)
#pragma unroll
            for (int pq = 0; pq < 4; pq++) acc_h[i][pq] *= Pf;
#pragma unroll
        for (int ks = 0; ks < 2; ks++) {
            bf16x8 af2[2], bfw[4];
#pragma unroll
            for (int i = 0; i < 2; i++) {
                int nrow = wave * 32 + i * 16 + l16;
                short e[8];
#pragma unroll
                for (int j = 0; j < 8; j++)
                    e[j] = BtL[ks * 32 + l4 * 8 + j][nrow];
                af2[i] = *(bf16x8*)e;
            }
#pragma unroll
            for (int pq = 0; pq < 4; pq++)
                bfw[pq] = *(const bf16x8*)&XdL[pq * 16 + l16][ks * 32 + l4 * 8];
#pragma unroll
            for (int i = 0; i < 2; i++)
#pragma unroll
                for (int pq = 0; pq < 4; pq++)
                    acc_h[i][pq] = __builtin_amdgcn_mfma_f32_16x16x32_bf16(af2[i], bfw[pq], acc_h[i][pq], 0, 0, 0);
        }
        __syncthreads();
    }

    float* Sp = S + (size_t)c * SELEMS + ((size_t)(b * NH + hh) * HD) * DSTATE;
#pragma unroll
    for (int i = 0; i < 2; i++)
#pragma unroll
        for (int pq = 0; pq < 4; pq++) {
            int nb = wave * 32 + i * 16 + (l4 << 2);
            int p = pq * 16 + l16;
            *(f32x4*)(Sp + (size_t)p * DSTATE + nb) = acc_h[i][pq];
        }
    if (tid == 0) P[(c * BB + b) * NH + hh] = expf(Lsum);
}

// ---------------- Kernel 5b: sequential chunk combine ----------------
__global__ __launch_bounds__(256) void scan_combine_kernel(const float* __restrict__ h0,
                                                           const float* __restrict__ P,
                                                           float* __restrict__ S,
                                                           float* __restrict__ hT) {
    size_t tid = (size_t)blockIdx.x * 256 + threadIdx.x;
    int hh = (int)((tid >> 13) & 31);
    int b = (int)(tid >> 18);
    float h = h0[tid];
#pragma unroll
    for (int c = 0; c < NC; c++) {
        float s = S[(size_t)c * SELEMS + tid];
        S[(size_t)c * SELEMS + tid] = h;
        h = fmaf(P[(c * BB + b) * NH + hh], h, s);
    }
    hT[tid] = h;
}

// ---------------- Kernel 5c: SSD emit (prefix fused into P0; 4 barriers/fc) ----------------
__global__ __launch_bounds__(256, 2) void scan_emit_ssd(const short* __restrict__ xBC,
                                                        const float* __restrict__ dtg,
                                                        const float* __restrict__ A_log,
                                                        const float* __restrict__ S,
                                                        const float* __restrict__ Dp,
                                                        short* __restrict__ ybq) {
    int tid = threadIdx.x;
    int wave = tid >> 6, lane = tid & 63;
    int l4 = lane >> 4, l16 = lane & 15;
    int c = blockIdx.x, hh = blockIdx.y, b = blockIdx.z;
    int cbase = c * CL;

    __shared__ __align__(16) short CtL[64][136];
    __shared__ __align__(16) short BtL[64][136];
    __shared__ __align__(16) short hL[64][132];
    __shared__ __align__(16) short XdL[64][72];
    __shared__ __align__(16) short XdwL[64][72];
    __shared__ __align__(16) short ML[64][72];
    __shared__ __align__(16) float sdt[64];
    __shared__ __align__(16) float sL[64];
    __shared__ __align__(16) float sW[64];
    __shared__ __align__(16) float sRdt[64];

    f32x4 acc_h[2][4];
    {
        const float* Sp = S + (size_t)c * SELEMS + ((size_t)(b * NH + hh) * HD) * DSTATE;
#pragma unroll
        for (int i = 0; i < 2; i++)
#pragma unroll
            for (int pq = 0; pq < 4; pq++) {
                int nb = wave * 32 + i * 16 + (l4 << 2);
                int p = pq * 16 + l16;
                acc_h[i][pq] = *(const f32x4*)(Sp + (size_t)p * DSTATE + nb);
            }
    }

    float expA = expf(A_log[hh]);
    float Dh = Dp[hh];
    const float* dtb = dtg + (size_t)b * TT * NH + hh;
    const short* xb = xBC + (size_t)b * TT * CD;
    short* yb = ybq + (size_t)b * TT * DI + hh * HD;

    int tg = wave >> 1;
    int sg = wave & 1;

#pragma unroll 1
    for (int f = 0; f < FPC; f++) {
        int t0 = cbase + f * FL;

        if (tid < 64) {
            float val = dtb[(size_t)(t0 + tid) * NH];
            sdt[tid] = val;
            float v = -expA * val;
#pragma unroll
            for (int off = 1; off < 64; off <<= 1) {
                float u = __shfl_up(v, off);
                if (lane >= off) v += u;
            }
            sL[tid] = v;
            float lt = __shfl(v, 63);
            sW[tid] = expf(lt - v);
            sRdt[tid] = 1.f / val;
        }
        {
            int r = tid >> 2, q = tid & 3;
            const short* cs = xb + (size_t)(t0 + r) * CD + DI + DSTATE + q * 32;
            const short* bs = xb + (size_t)(t0 + r) * CD + DI + q * 32;
#pragma unroll
            for (int j = 0; j < 4; j++) {
                *(bf16x8*)&CtL[r][q * 32 + j * 8] = *(const bf16x8*)(cs + j * 8);
                *(bf16x8*)&BtL[r][q * 32 + j * 8] = *(const bf16x8*)(bs + j * 8);
            }
        }
#pragma unroll
        for (int i = 0; i < 2; i++)
#pragma unroll
            for (int pq = 0; pq < 4; pq++) {
                int nb = wave * 32 + i * 16 + (l4 << 2);
                int p = pq * 16 + l16;
                *(short2*)&hL[p][nb] = make_short2(f2bs(acc_h[i][pq][0]), f2bs(acc_h[i][pq][1]));
                *(short2*)&hL[p][nb + 2] = make_short2(f2bs(acc_h[i][pq][2]), f2bs(acc_h[i][pq][3]));
            }
        __syncthreads();

        {
            int s = tid & 63, pg = tid >> 6;
            const short* xs = xb + (size_t)(t0 + s) * CD + hh * HD + pg * 16;
            float dts = sdt[s];
            float dw = dts * sW[s];
            bf16x8 v0 = *(const bf16x8*)xs;
            bf16x8 v1 = *(const bf16x8*)(xs + 8);
#pragma unroll
            for (int j = 0; j < 8; j++) {
                float xv = b2f(v0[j]);
                XdL[pg * 16 + j][s] = f2bs(xv * dts);
                XdwL[pg * 16 + j][s] = f2bs(xv * dw);
            }
#pragma unroll
            for (int j = 0; j < 8; j++) {
                float xv = b2f(v1[j]);
                XdL[pg * 16 + 8 + j][s] = f2bs(xv * dts);
                XdwL[pg * 16 + 8 + j][s] = f2bs(xv * dw);
            }
        }
        __syncthreads();

        {
            f32x4 g[2][2] = {};
#pragma unroll
            for (int ks = 0; ks < 4; ks++) {
                bf16x8 af[2], bfm[2];
#pragma unroll
                for (int i = 0; i < 2; i++)
                    af[i] = *(const bf16x8*)&CtL[tg * 32 + i * 16 + l16][ks * 32 + l4 * 8];
#pragma unroll
                for (int n = 0; n < 2; n++)
                    bfm[n] = *(const bf16x8*)&BtL[sg * 32 + n * 16 + l16][ks * 32 + l4 * 8];
#pragma unroll
                for (int i = 0; i < 2; i++)
#pragma unroll
                    for (int n = 0; n < 2; n++)
                        g[i][n] = __builtin_amdgcn_mfma_f32_16x16x32_bf16(af[i], bfm[n], g[i][n], 0, 0, 0);
            }
#pragma unroll
            for (int i = 0; i < 2; i++) {
                int tb2 = tg * 32 + i * 16 + (l4 << 2);
                float4 Lt = *(const float4*)&sL[tb2];
                float Ltr[4] = {Lt.x, Lt.y, Lt.z, Lt.w};
#pragma unroll
                for (int n = 0; n < 2; n++) {
                    int sE = sg * 32 + n * 16 + l16;
                    float Ls = sL[sE];
#pragma unroll
                    for (int r2 = 0; r2 < 4; r2++) {
                        float m = (sE <= tb2 + r2) ? g[i][n][r2] * expf(Ltr[r2] - Ls) : 0.f;
                        ML[tb2 + r2][sE] = f2bs(m);
                    }
                }
            }
        }
        __syncthreads();

        {
            f32x4 ay[2][2] = {};
            f32x4 ai[2][2] = {};
#pragma unroll
            for (int ks = 0; ks < 2; ks++) {
                bf16x8 af[2], bfp[2];
#pragma unroll
                for (int i = 0; i < 2; i++)
                    af[i] = *(const bf16x8*)&ML[tg * 32 + i * 16 + l16][ks * 32 + l4 * 8];
#pragma unroll
                for (int n = 0; n < 2; n++)
                    bfp[n] = *(const bf16x8*)&XdL[sg * 32 + n * 16 + l16][ks * 32 + l4 * 8];
#pragma unroll
                for (int i = 0; i < 2; i++)
#pragma unroll
                    for (int n = 0; n < 2; n++)
                        ay[i][n] = __builtin_amdgcn_mfma_f32_16x16x32_bf16(af[i], bfp[n], ay[i][n], 0, 0, 0);
            }
#pragma unroll
            for (int ks = 0; ks < 4; ks++) {
                bf16x8 af[2], bfh[2];
#pragma unroll
                for (int i = 0; i < 2; i++)
                    af[i] = *(const bf16x8*)&CtL[tg * 32 + i * 16 + l16][ks * 32 + l4 * 8];
#pragma unroll
                for (int n = 0; n < 2; n++) {
                    int prow = sg * 32 + n * 16 + l16;
                    int kb = ks * 32 + l4 * 8;
                    union { bf16x8 v; uint2 u2[2]; } hu;
                    hu.u2[0] = *(const uint2*)&hL[prow][kb];
                    hu.u2[1] = *(const uint2*)&hL[prow][kb + 4];
                    bfh[n] = hu.v;
                }
#pragma unroll
                for (int i = 0; i < 2; i++)
#pragma unroll
                    for (int n = 0; n < 2; n++)
                        ai[i][n] = __builtin_amdgcn_mfma_f32_16x16x32_bf16(af[i], bfh[n], ai[i][n], 0, 0, 0);
            }
            float Lft = sL[63];
#pragma unroll
            for (int i = 0; i < 2; i++) {
                int tb2 = tg * 32 + i * 16 + (l4 << 2);
                float4 Lt = *(const float4*)&sL[tb2];
                float4 Rt = *(const float4*)&sRdt[tb2];
                float Ltr[4] = {Lt.x, Lt.y, Lt.z, Lt.w};
                float Rtr[4] = {Rt.x, Rt.y, Rt.z, Rt.w};
#pragma unroll
                for (int n = 0; n < 2; n++) {
                    int p = sg * 32 + n * 16 + l16;
#pragma unroll
                    for (int r2 = 0; r2 < 4; r2++) {
                        float xv = b2f(XdL[p][tb2 + r2]) * Rtr[r2];
                        float yv = ay[i][n][r2] + expf(Ltr[r2]) * ai[i][n][r2] + Dh * xv;
                        yb[(size_t)(t0 + tb2 + r2) * DI + p] = f2bs(yv);
                    }
                }
            }
            float Pf = expf(Lft);
#pragma unroll
            for (int i = 0; i < 2; i++)
#pragma unroll
                for (int pq = 0; pq < 4; pq++)
                    acc_h[i][pq] *= Pf;
#pragma unroll
            for (int ks = 0; ks < 2; ks++) {
                bf16x8 af2[2], bfw[4];
#pragma unroll
                for (int i = 0; i < 2; i++) {
                    int nrow = wave * 32 + i * 16 + l16;
                    short e[8];
#pragma unroll
                    for (int j = 0; j < 8; j++)
                        e[j] = BtL[ks * 32 + l4 * 8 + j][nrow];
                    af2[i] = *(bf16x8*)e;
                }
#pragma unroll
                for (int pq = 0; pq < 4; pq++)
                    bfw[pq] = *(const bf16x8*)&XdwL[pq * 16 + l16][ks * 32 + l4 * 8];
#pragma unroll
                for (int i = 0; i < 2; i++)
#pragma unroll
                    for (int pq = 0; pq < 4; pq++)
                        acc_h[i][pq] = __builtin_amdgcn_mfma_f32_16x16x32_bf16(af2[i], bfw[pq], acc_h[i][pq], 0, 0, 0);
            }
        }
        __syncthreads();
    }
}

// ---------------- Kernel 6: gating + RMSNorm (bf16 y, bf16 z) -> bf16 g ----------------
__global__ __launch_bounds__(256) void gate_rms_kernel(const short* __restrict__ ybq,
                                                       const short* __restrict__ zx,
                                                       const float* __restrict__ rw,
                                                       __hip_bfloat16* __restrict__ gq) {
    int m = blockIdx.x;
    int tid = threadIdx.x;
    const short* yr = ybq + (size_t)m * DI;
    const short* zr = zx + (size_t)m * DIP;
    int base = tid * 8;
    float gv[8];
    float ss = 0.f;
    bf16x8 yv8 = *(const bf16x8*)(yr + base);
    bf16x8 zv8 = *(const bf16x8*)(zr + base);
#pragma unroll
    for (int i = 0; i < 8; i++) {
        float y = b2f(yv8[i]);
        float z = b2f(zv8[i]);
        float sg = 1.f / (1.f + expf(-z));
        float gg = y * z * sg;
        gv[i] = gg;
        ss += gg * gg;
    }
#pragma unroll
    for (int off = 1; off < 64; off <<= 1) ss += __shfl_xor(ss, off);
    __shared__ float red[4];
    int w = tid >> 6;
    if ((tid & 63) == 0) red[w] = ss;
    __syncthreads();
    float tot = red[0] + red[1] + red[2] + red[3];
    float r = rsqrtf(tot * (1.f / DI) + 1e-5f);
#pragma unroll
    for (int i = 0; i < 8; i += 2) {
        __hip_bfloat162 p;
        p.x = __float2bfloat16(gv[i] * r * rw[base + i]);
        p.y = __float2bfloat16(gv[i + 1] * r * rw[base + i + 1]);
        *(__hip_bfloat162*)(gq + (size_t)m * DI + base + i) = p;
    }
}

// ---------------- Kernel 7: GEMM2 bf16 MFMA (T2 swizzle + T1 remap m-inner, transposed store) ----------------
__global__ __launch_bounds__(256) void gemm2_mfma(const __hip_bfloat16* __restrict__ gq,
                                                  const __hip_bfloat16* __restrict__ Wob,
                                                  float* __restrict__ out) {
    __shared__ short As[128][64];
    __shared__ short Bs[128][64];
    int tid = threadIdx.x;
    int lane = tid & 63;
    int wave = tid >> 6;
    int wr = wave >> 1, wc = wave & 1;
    int id = blockIdx.x;
    int xcd = id & 7;
    int pos = id >> 3;
    int j0 = (pos >> 3) * 128;
    int m0 = (xcd * 8 + (pos & 7)) * 128;
    int srow = tid >> 3;
    int skc = (((tid & 7) ^ ((tid >> 3) & 7)) * 8);

    f32x4 acc[4][4] = {};

    for (int k0 = 0; k0 < DI; k0 += 64) {
        __syncthreads();
#pragma unroll
        for (int q = 0; q < 4; q++) {
            gload16(gq + (size_t)(m0 + q * 32 + srow) * DI + k0 + skc,
                    ((short*)As) + q * 2048 + wave * 512);
            gload16(Wob + (size_t)(j0 + q * 32 + srow) * DI + k0 + skc,
                    ((short*)Bs) + q * 2048 + wave * 512);
        }
        asm volatile("s_waitcnt vmcnt(0)" ::: "memory");
        __syncthreads();
#pragma unroll
        for (int ks = 0; ks < 2; ks++) {
            int pch = (((ks * 4) + (lane >> 4)) ^ (lane & 7)) * 8;
            bf16x8 af[4], bfr[4];
#pragma unroll
            for (int i = 0; i < 4; i++)
                af[i] = *(const bf16x8*)&As[wr * 64 + i * 16 + (lane & 15)][pch];
#pragma unroll
            for (int n = 0; n < 4; n++)
                bfr[n] = *(const bf16x8*)&Bs[wc * 64 + n * 16 + (lane & 15)][pch];
#pragma unroll
            for (int i = 0; i < 4; i++)
#pragma unroll
                for (int n = 0; n < 4; n++)
                    acc[i][n] = __builtin_amdgcn_mfma_f32_16x16x32_bf16(af[i], bfr[n], acc[i][n], 0, 0, 0);
        }
    }
#pragma unroll
    for (int i = 0; i < 4; i++) {
        int m = m0 + wr * 64 + i * 16 + ((lane >> 4) << 2);
        int b = m >> 12;
        int t = m & 4095;
#pragma unroll
        for (int n = 0; n < 4; n++) {
            int j = j0 + wc * 64 + n * 16 + (lane & 15);
            *(f32x4*)(out + (size_t)b * DM * TT + (size_t)j * TT + t) = acc[i][n];
        }
    }
}

extern "C" void kernel_launch(void* const* d_in, const int* in_sizes, int n_in,
                              void* d_out, int out_size, void* d_ws, size_t ws_size,
                              hipStream_t stream) {
    const float* x       = (const float*)d_in[0];
    const float* ln_w    = (const float*)d_in[1];
    const float* ln_b    = (const float*)d_in[2];
    const float* W_in    = (const float*)d_in[3];
    const float* conv_w  = (const float*)d_in[4];
    const float* conv_b  = (const float*)d_in[5];
    const float* dt_bias = (const float*)d_in[6];
    const float* A_log   = (const float*)d_in[7];
    const float* Dp      = (const float*)d_in[8];
    const float* rms_w   = (const float*)d_in[9];
    const float* W_out   = (const float*)d_in[10];
    const float* h0      = (const float*)d_in[11];

    float* out = (float*)d_out;
    float* hT = out + (size_t)BB * DM * TT;

    char* ws = (char*)d_ws;
    // Workspace layout — total 211,355,648 bytes:
    float* mu   = (float*)(ws + 0);
    float* rs   = (float*)(ws + 32768);
    short* zxq  = (short*)(ws + 65536);                   //  71,827,456  (B,T,4384) bf16
    short* xBCq = (short*)(ws + 71892992);                //  37,748,736  (B,T,2304) bf16
    __hip_bfloat16* gq  = (__hip_bfloat16*)(ws + 71892992);
    __hip_bfloat16* Wob = (__hip_bfloat16*)(ws + 105447424);
    short* ybq  = (short*)(ws + 109641728);               //  33,554,432  (B,T,2048) bf16
    __hip_bfloat16* Wb  = (__hip_bfloat16*)(ws + 109641728);
    float* dtv  = (float*)(ws + 176750592);
    __hip_bfloat16* xnb = (__hip_bfloat16*)(ws + 177799168);
    float* S    = (float*)(ws + 177799168);
    float* P    = (float*)(ws + 194576384);
    float* dpart = (float*)(ws + 194578432);              //  16,777,216

    ln_stats_kernel<<<(TT / 32) * BB, 256, 0, stream>>>(x, mu, rs);
    xn_kernel<<<dim3(TT / 64, DM / 64, BB), 256, 0, stream>>>(x, mu, rs, ln_w, ln_b, xnb);
    cvt_pad_kernel<<<(NP1 * DM) / 1024, 256, 0, stream>>>(W_in, Wb, DIP * DM, NP1 * DM);
    gemm1_mfma256<<<(NP1 / 128) * ((BB * TT) / 256), 512, 0, stream>>>(Wb, xnb, zxq);
    gemm1_strip<<<dim3(KSPLIT, (BB * TT) / 64), 256, 0, stream>>>(x, mu, rs, ln_w, ln_b, W_in, dpart);
    dt_reduce_kernel<<<(BB * TT * NH) / 256, 256, 0, stream>>>(dpart, dt_bias, dtv);
    conv_kernel<<<(BB * (TT / 4) * (CD / 8)) / 256, 256, 0, stream>>>(zxq, conv_w, conv_b, xBCq);
    scan_reduce_ssd<<<dim3(NC, NH, BB), 256, 0, stream>>>(xBCq, dtv, A_log, S, P);
    scan_combine_kernel<<<(int)(SELEMS / 256), 256, 0, stream>>>(h0, P, S, hT);
    scan_emit_ssd<<<dim3(NC, NH, BB), 256, 0, stream>>>(xBCq, dtv, A_log, S, Dp, ybq);
    cvt_pad_kernel<<<(DM * DI) / 1024, 256, 0, stream>>>(W_out, Wob, DM * DI, DM * DI);
    gate_rms_kernel<<<BB * TT, 256, 0, stream>>>(ybq, zxq, rms_w, gq);
    gemm2_mfma<<<((BB * TT) / 128) * (DM / 128), 256, 0, stream>>>(gq, Wob, out);
}

// Round 19
// 319.293 us; speedup vs baseline: 1.0495x; 1.0396x over previous
//
#include <hip/hip_runtime.h>
#include <hip/hip_bf16.h>
#include <math.h>

// Problem constants
#define BB 2
#define TT 4096
#define DM 1024
#define DSTATE 128
#define DI 2048
#define HD 64
#define NH 32
#define DIP 4384   // 2*DI + 2*DSTATE + NH
#define CD 2304    // DI + 2*DSTATE

// Chunked scan parameters
#define NC 8
#define CL 512
#define FL 64            // SSD fine-chunk length
#define FPC (CL / FL)    // 8
#define SELEMS ((size_t)BB * NH * HD * DSTATE)   // 524288

#define NP1 4480   // DIP padded to multiple of 128 for MFMA staging
#define KSPLIT 16  // split-K factor for the dt strip GEMM

typedef __attribute__((ext_vector_type(8))) short bf16x8;
typedef __attribute__((ext_vector_type(4))) float f32x4;

__device__ inline void gload16(const void* g, void* l) {
    __builtin_amdgcn_global_load_lds(
        (const __attribute__((address_space(1))) void*)g,
        (__attribute__((address_space(3))) void*)l, 16, 0, 0);
}

__device__ inline short f2bs(float f) {
    __hip_bfloat16 h = __float2bfloat16(f);
    union { __hip_bfloat16 h; short s; } u;
    u.h = h;
    return u.s;
}
__device__ inline float b2f(short s) {
    union { float f; unsigned u; } u;
    u.u = ((unsigned)(unsigned short)s) << 16;
    return u.f;
}

// ---------------- Kernel 1: LayerNorm statistics (split-D, 256 blocks) ----------------
__global__ __launch_bounds__(256) void ln_stats_kernel(const float* __restrict__ x,
                                                       float* __restrict__ mu,
                                                       float* __restrict__ rs) {
    __shared__ float sred[2][8][32];
    int tid = threadIdx.x;
    int tl = tid & 31;
    int ds = tid >> 5;               // 0..7
    int t = (blockIdx.x & 127) * 32 + tl;
    int b = blockIdx.x >> 7;
    const float* xb = x + (size_t)b * DM * TT + (size_t)ds * 128 * TT + t;
    float s = 0.f, ss = 0.f;
#pragma unroll 8
    for (int d = 0; d < 128; d++) {
        float v = xb[(size_t)d * TT];
        s += v;
        ss += v * v;
    }
    sred[0][ds][tl] = s;
    sred[1][ds][tl] = ss;
    __syncthreads();
    if (tid < 32) {
        float st = 0.f, sst = 0.f;
#pragma unroll
        for (int q = 0; q < 8; q++) { st += sred[0][q][tid]; sst += sred[1][q][tid]; }
        float m = st * (1.f / DM);
        float var = sst * (1.f / DM) - m * m;
        int idx = b * TT + (blockIdx.x & 127) * 32 + tid;
        mu[idx] = m;
        rs[idx] = rsqrtf(var + 1e-5f);
    }
}

// ---------------- Kernel 1b: xn = LN(x) transposed to (m, k) in bf16 ----------------
__global__ __launch_bounds__(256) void xn_kernel(const float* __restrict__ x,
                                                 const float* __restrict__ mu,
                                                 const float* __restrict__ rs,
                                                 const float* __restrict__ ln_w,
                                                 const float* __restrict__ ln_b,
                                                 __hip_bfloat16* __restrict__ xn) {
    __shared__ float tile[64][65];
    int tid = threadIdx.x;
    int t0 = blockIdx.x * 64, d0 = blockIdx.y * 64, b = blockIdx.z;
#pragma unroll
    for (int i = 0; i < 64; i += 4) {
        int dl = i + (tid >> 6);
        tile[dl][tid & 63] = x[(size_t)b * DM * TT + (size_t)(d0 + dl) * TT + t0 + (tid & 63)];
    }
    __syncthreads();
#pragma unroll
    for (int i = 0; i < 64; i += 8) {
        int tl = i + (tid >> 5);
        int kk = (tid & 31) * 2;
        int m = b * TT + t0 + tl;
        float mu_m = mu[m], rs_m = rs[m];
        float v0 = (tile[kk][tl] - mu_m) * rs_m * ln_w[d0 + kk] + ln_b[d0 + kk];
        float v1 = (tile[kk + 1][tl] - mu_m) * rs_m * ln_w[d0 + kk + 1] + ln_b[d0 + kk + 1];
        __hip_bfloat162 pk;
        pk.x = __float2bfloat16(v0);
        pk.y = __float2bfloat16(v1);
        *(__hip_bfloat162*)(xn + (size_t)m * DM + d0 + kk) = pk;
    }
}

// ---------------- convert f32 -> bf16 with zero-padding ----------------
__global__ __launch_bounds__(256) void cvt_pad_kernel(const float* __restrict__ src,
                                                      __hip_bfloat16* __restrict__ dst,
                                                      int src_n, int tot_n) {
    int i = (blockIdx.x * 256 + threadIdx.x) * 4;
    if (i >= tot_n) return;
    float4 v = (i < src_n) ? *(const float4*)(src + i) : make_float4(0.f, 0.f, 0.f, 0.f);
    __hip_bfloat162 p0, p1;
    p0.x = __float2bfloat16(v.x); p0.y = __float2bfloat16(v.y);
    p1.x = __float2bfloat16(v.z); p1.y = __float2bfloat16(v.w);
    *(__hip_bfloat162*)(dst + i) = p0;
    *(__hip_bfloat162*)(dst + i + 2) = p1;
}

// ---------------- Kernel 2: GEMM1 bf16 MFMA (T2 swizzle + T1 remap, m-inner) — PROVEN 128x128 ----------------
__global__ __launch_bounds__(256) void gemm1_mfma(const __hip_bfloat16* __restrict__ Wb,
                                                  const __hip_bfloat16* __restrict__ xn,
                                                  short* __restrict__ zx) {
    __shared__ short As[128][64];
    __shared__ short Bs[128][64];
    int tid = threadIdx.x;
    int lane = tid & 63;
    int wave = tid >> 6;
    int wr = wave >> 1, wc = wave & 1;
    int id = blockIdx.x;
    int xcd = id & 7;
    int pos = id >> 3;               // [0, 280)
    int j0 = (pos >> 3) * 128;       // j outer: 35 panels
    int m0 = (xcd * 8 + (pos & 7)) * 128;   // m inner: strip L2-resident
    int srow = tid >> 3;
    int skc = (((tid & 7) ^ ((tid >> 3) & 7)) * 8);   // pre-swizzled source k-chunk

    f32x4 acc[4][4] = {};

    for (int k0 = 0; k0 < DM; k0 += 64) {
        __syncthreads();
#pragma unroll
        for (int q = 0; q < 4; q++) {
            gload16(Wb + (size_t)(j0 + q * 32 + srow) * DM + k0 + skc,
                    ((short*)As) + q * 2048 + wave * 512);
            gload16(xn + (size_t)(m0 + q * 32 + srow) * DM + k0 + skc,
                    ((short*)Bs) + q * 2048 + wave * 512);
        }
        asm volatile("s_waitcnt vmcnt(0)" ::: "memory");
        __syncthreads();
#pragma unroll
        for (int ks = 0; ks < 2; ks++) {
            int pch = (((ks * 4) + (lane >> 4)) ^ (lane & 7)) * 8;
            bf16x8 af[4], bfr[4];
#pragma unroll
            for (int i = 0; i < 4; i++)
                af[i] = *(const bf16x8*)&As[wr * 64 + i * 16 + (lane & 15)][pch];
#pragma unroll
            for (int n = 0; n < 4; n++)
                bfr[n] = *(const bf16x8*)&Bs[wc * 64 + n * 16 + (lane & 15)][pch];
#pragma unroll
            for (int i = 0; i < 4; i++)
#pragma unroll
                for (int n = 0; n < 4; n++)
                    acc[i][n] = __builtin_amdgcn_mfma_f32_16x16x32_bf16(af[i], bfr[n], acc[i][n], 0, 0, 0);
        }
    }
#pragma unroll
    for (int i = 0; i < 4; i++) {
        int j = j0 + wr * 64 + i * 16 + ((lane >> 4) << 2);
        if (j < DIP) {
#pragma unroll
            for (int n = 0; n < 4; n++) {
                int m = m0 + wc * 64 + n * 16 + (lane & 15);
                short4 s4;
                s4.x = f2bs(acc[i][n][0]); s4.y = f2bs(acc[i][n][1]);
                s4.z = f2bs(acc[i][n][2]); s4.w = f2bs(acc[i][n][3]);
                *(short4*)(zx + (size_t)m * DIP + j) = s4;
            }
        }
    }
}

// ---------------- Kernel 2b: split-K f32 strip GEMM for dt cols -> partial sums ----------------
__global__ __launch_bounds__(256) void gemm1_strip(const float* __restrict__ x,
                                                   const float* __restrict__ mu,
                                                   const float* __restrict__ rs,
                                                   const float* __restrict__ ln_w,
                                                   const float* __restrict__ ln_b,
                                                   const float* __restrict__ Win,
                                                   float* __restrict__ partial) {
    __shared__ float As[16][64];
    __shared__ float Ws[64][17];
    int tid = threadIdx.x;
    int tx = tid & 15;
    int ty = tid >> 4;
    int j0 = 4352;
    int kq = blockIdx.x;
    int m0 = blockIdx.y * 64;
    int b = m0 >> 12;
    int t0 = m0 & 4095;
    const float* Xb = x + (size_t)b * DM * TT + t0;

    int lr = tid >> 4;
    int lc = (tid & 15) * 4;
    int wr = tid >> 2;
    int wc = (tid & 3) * 4;

    float acc[4][4] = {};
    int kbeg = kq * (DM / KSPLIT);
    for (int k0 = kbeg; k0 < kbeg + DM / KSPLIT; k0 += 16) {
        float4 xv = *(const float4*)(Xb + (size_t)(k0 + lr) * TT + lc);
        float4 muv = *(const float4*)(&mu[m0 + lc]);
        float4 rsv = *(const float4*)(&rs[m0 + lc]);
        float lw = ln_w[k0 + lr], lb = ln_b[k0 + lr];
        As[lr][lc]     = (xv.x - muv.x) * rsv.x * lw + lb;
        As[lr][lc + 1] = (xv.y - muv.y) * rsv.y * lw + lb;
        As[lr][lc + 2] = (xv.z - muv.z) * rsv.z * lw + lb;
        As[lr][lc + 3] = (xv.w - muv.w) * rsv.w * lw + lb;

        int j = j0 + wr;
        float4 wv = make_float4(0.f, 0.f, 0.f, 0.f);
        if (j < DIP) wv = *(const float4*)(Win + (size_t)j * DM + k0 + wc);
        Ws[wr][wc] = wv.x; Ws[wr][wc + 1] = wv.y; Ws[wr][wc + 2] = wv.z; Ws[wr][wc + 3] = wv.w;
        __syncthreads();
#pragma unroll
        for (int kk = 0; kk < 16; kk++) {
            float4 a4 = *(const float4*)&As[kk][ty * 4];
            float a[4] = {a4.x, a4.y, a4.z, a4.w};
            float bv[4];
#pragma unroll
            for (int n = 0; n < 4; n++) bv[n] = Ws[tx * 4 + n][kk];
#pragma unroll
            for (int i = 0; i < 4; i++)
#pragma unroll
                for (int n = 0; n < 4; n++)
                    acc[i][n] = fmaf(a[i], bv[n], acc[i][n]);
        }
        __syncthreads();
    }
#pragma unroll
    for (int i = 0; i < 4; i++) {
        int m = m0 + ty * 4 + i;
        int hh = tx * 4;
        if (hh < NH) {
            float4 v = make_float4(acc[i][0], acc[i][1], acc[i][2], acc[i][3]);
            *(float4*)(partial + ((size_t)kq * BB * TT + m) * NH + hh) = v;
        }
    }
}

// ---------------- Kernel 2c: reduce split-K partials + bias + softplus -> dtv ----------------
__global__ __launch_bounds__(256) void dt_reduce_kernel(const float* __restrict__ partial,
                                                        const float* __restrict__ dt_bias,
                                                        float* __restrict__ dtv) {
    int i = blockIdx.x * 256 + threadIdx.x;
    int hh = i & (NH - 1);
    float s = 0.f;
#pragma unroll
    for (int kq = 0; kq < KSPLIT; kq++)
        s += partial[(size_t)kq * BB * TT * NH + i];
    float raw = s + dt_bias[hh];
    dtv[i] = (raw > 20.f) ? raw : log1pf(expf(raw));
}

// ---------------- Kernel 3: causal depthwise conv(4) + SiLU — 4t x 8ch register reuse ----------------
__global__ __launch_bounds__(256) void conv_kernel(const short* __restrict__ zx,
                                                   const float* __restrict__ cw,
                                                   const float* __restrict__ cb,
                                                   short* __restrict__ xBC) {
    int gid = blockIdx.x * 256 + threadIdx.x;
    int cq = gid % (CD / 8);
    int tq = (gid / (CD / 8)) % (TT / 4);
    int b  = gid / ((CD / 8) * (TT / 4));
    int c = cq * 8, tb = tq * 4;
    const short* src = zx + (size_t)b * TT * DIP + DI + c;

    float wv[8][4];
    float acc[4][8];
#pragma unroll
    for (int e = 0; e < 8; e++) {
        float4 w4 = *(const float4*)(cw + (c + e) * 4);
        wv[e][0] = w4.x; wv[e][1] = w4.y; wv[e][2] = w4.z; wv[e][3] = w4.w;
        float bias = cb[c + e];
#pragma unroll
        for (int o = 0; o < 4; o++) acc[o][e] = bias;
    }

#pragma unroll
    for (int r = 0; r < 7; r++) {
        int ts = tb - 3 + r;
        if (ts >= 0) {
            bf16x8 v = *(const bf16x8*)(src + (size_t)ts * DIP);
            float rowf[8];
#pragma unroll
            for (int e = 0; e < 8; e++) rowf[e] = b2f(v[e]);
#pragma unroll
            for (int o = 0; o < 4; o++) {
                if (o <= r && r <= o + 3) {
                    int k = r - o;
#pragma unroll
                    for (int e = 0; e < 8; e++)
                        acc[o][e] = fmaf(wv[e][k], rowf[e], acc[o][e]);
                }
            }
        }
    }
#pragma unroll
    for (int o = 0; o < 4; o++) {
        short out[8];
#pragma unroll
        for (int e = 0; e < 8; e++) {
            float sg = 1.f / (1.f + expf(-acc[o][e]));
            out[e] = f2bs(acc[o][e] * sg);
        }
        *(bf16x8*)(xBC + ((size_t)b * TT + tb + o) * CD + c) = *(bf16x8*)out;
    }
}

// ---------------- Kernel 5a: SSD chunk reduce (prefix fused into P0; 3 barriers/fc) ----------------
__global__ __launch_bounds__(256, 2) void scan_reduce_ssd(const short* __restrict__ xBC,
                                                          const float* __restrict__ dtg,
                                                          const float* __restrict__ A_log,
                                                          float* __restrict__ S,
                                                          float* __restrict__ P) {
    int tid = threadIdx.x;
    int wave = tid >> 6, lane = tid & 63;
    int l4 = lane >> 4, l16 = lane & 15;
    int c = blockIdx.x, hh = blockIdx.y, b = blockIdx.z;
    int cbase = c * CL;

    __shared__ __align__(16) short BtL[64][136];
    __shared__ __align__(16) short XdL[64][72];
    __shared__ __align__(16) float sdt[64];
    __shared__ __align__(16) float sL[64];
    __shared__ __align__(16) float sW[64];

    f32x4 acc_h[2][4];
#pragma unroll
    for (int i = 0; i < 2; i++)
#pragma unroll
        for (int pq = 0; pq < 4; pq++) acc_h[i][pq] = (f32x4){0.f, 0.f, 0.f, 0.f};
    float Lsum = 0.f;

    float expA = expf(A_log[hh]);
    const float* dtb = dtg + (size_t)b * TT * NH + hh;
    const short* xb = xBC + (size_t)b * TT * CD;

#pragma unroll 1
    for (int f = 0; f < FPC; f++) {
        int t0 = cbase + f * FL;
        if (tid < 64) {
            float val = dtb[(size_t)(t0 + tid) * NH];
            sdt[tid] = val;
            float v = -expA * val;
#pragma unroll
            for (int off = 1; off < 64; off <<= 1) {
                float u = __shfl_up(v, off);
                if (lane >= off) v += u;
            }
            sL[tid] = v;
            float lt = __shfl(v, 63);
            sW[tid] = expf(lt - v);
        }
        {
            int r = tid >> 2, q = tid & 3;
            const short* bs = xb + (size_t)(t0 + r) * CD + DI + q * 32;
#pragma unroll
            for (int j = 0; j < 4; j++)
                *(bf16x8*)&BtL[r][q * 32 + j * 8] = *(const bf16x8*)(bs + j * 8);
        }
        __syncthreads();
        {
            int s = tid & 63, pg2 = tid >> 6;
            const short* xs = xb + (size_t)(t0 + s) * CD + hh * HD + pg2 * 16;
            float dw = sdt[s] * sW[s];
            bf16x8 v0 = *(const bf16x8*)xs;
            bf16x8 v1 = *(const bf16x8*)(xs + 8);
#pragma unroll
            for (int j = 0; j < 8; j++) XdL[pg2 * 16 + j][s] = f2bs(b2f(v0[j]) * dw);
#pragma unroll
            for (int j = 0; j < 8; j++) XdL[pg2 * 16 + 8 + j][s] = f2bs(b2f(v1[j]) * dw);
        }
        __syncthreads();
        float Lft = sL[63];
        float Pf = expf(Lft);
        Lsum += Lft;
#pragma unroll
        for (int i = 0; i < 2; i++)
#pragma unroll
            for (int pq = 0; pq < 4; pq++) acc_h[i][pq] *= Pf;
#pragma unroll
        for (int ks = 0; ks < 2; ks++) {
            bf16x8 af2[2], bfw[4];
#pragma unroll
            for (int i = 0; i < 2; i++) {
                int nrow = wave * 32 + i * 16 + l16;
                short e[8];
#pragma unroll
                for (int j = 0; j < 8; j++)
                    e[j] = BtL[ks * 32 + l4 * 8 + j][nrow];
                af2[i] = *(bf16x8*)e;
            }
#pragma unroll
            for (int pq = 0; pq < 4; pq++)
                bfw[pq] = *(const bf16x8*)&XdL[pq * 16 + l16][ks * 32 + l4 * 8];
#pragma unroll
            for (int i = 0; i < 2; i++)
#pragma unroll
                for (int pq = 0; pq < 4; pq++)
                    acc_h[i][pq] = __builtin_amdgcn_mfma_f32_16x16x32_bf16(af2[i], bfw[pq], acc_h[i][pq], 0, 0, 0);
        }
        __syncthreads();
    }

    float* Sp = S + (size_t)c * SELEMS + ((size_t)(b * NH + hh) * HD) * DSTATE;
#pragma unroll
    for (int i = 0; i < 2; i++)
#pragma unroll
        for (int pq = 0; pq < 4; pq++) {
            int nb = wave * 32 + i * 16 + (l4 << 2);
            int p = pq * 16 + l16;
            *(f32x4*)(Sp + (size_t)p * DSTATE + nb) = acc_h[i][pq];
        }
    if (tid == 0) P[(c * BB + b) * NH + hh] = expf(Lsum);
}

// ---------------- Kernel 5b: sequential chunk combine ----------------
__global__ __launch_bounds__(256) void scan_combine_kernel(const float* __restrict__ h0,
                                                           const float* __restrict__ P,
                                                           float* __restrict__ S,
                                                           float* __restrict__ hT) {
    size_t tid = (size_t)blockIdx.x * 256 + threadIdx.x;
    int hh = (int)((tid >> 13) & 31);
    int b = (int)(tid >> 18);
    float h = h0[tid];
#pragma unroll
    for (int c = 0; c < NC; c++) {
        float s = S[(size_t)c * SELEMS + tid];
        S[(size_t)c * SELEMS + tid] = h;
        h = fmaf(P[(c * BB + b) * NH + hh], h, s);
    }
    hT[tid] = h;
}

// ---------------- Kernel 5c: SSD emit (prefix fused into P0; 4 barriers/fc) ----------------
__global__ __launch_bounds__(256, 2) void scan_emit_ssd(const short* __restrict__ xBC,
                                                        const float* __restrict__ dtg,
                                                        const float* __restrict__ A_log,
                                                        const float* __restrict__ S,
                                                        const float* __restrict__ Dp,
                                                        short* __restrict__ ybq) {
    int tid = threadIdx.x;
    int wave = tid >> 6, lane = tid & 63;
    int l4 = lane >> 4, l16 = lane & 15;
    int c = blockIdx.x, hh = blockIdx.y, b = blockIdx.z;
    int cbase = c * CL;

    __shared__ __align__(16) short CtL[64][136];
    __shared__ __align__(16) short BtL[64][136];
    __shared__ __align__(16) short hL[64][132];
    __shared__ __align__(16) short XdL[64][72];
    __shared__ __align__(16) short XdwL[64][72];
    __shared__ __align__(16) short ML[64][72];
    __shared__ __align__(16) float sdt[64];
    __shared__ __align__(16) float sL[64];
    __shared__ __align__(16) float sW[64];
    __shared__ __align__(16) float sRdt[64];

    f32x4 acc_h[2][4];
    {
        const float* Sp = S + (size_t)c * SELEMS + ((size_t)(b * NH + hh) * HD) * DSTATE;
#pragma unroll
        for (int i = 0; i < 2; i++)
#pragma unroll
            for (int pq = 0; pq < 4; pq++) {
                int nb = wave * 32 + i * 16 + (l4 << 2);
                int p = pq * 16 + l16;
                acc_h[i][pq] = *(const f32x4*)(Sp + (size_t)p * DSTATE + nb);
            }
    }

    float expA = expf(A_log[hh]);
    float Dh = Dp[hh];
    const float* dtb = dtg + (size_t)b * TT * NH + hh;
    const short* xb = xBC + (size_t)b * TT * CD;
    short* yb = ybq + (size_t)b * TT * DI + hh * HD;

    int tg = wave >> 1;
    int sg = wave & 1;

#pragma unroll 1
    for (int f = 0; f < FPC; f++) {
        int t0 = cbase + f * FL;

        if (tid < 64) {
            float val = dtb[(size_t)(t0 + tid) * NH];
            sdt[tid] = val;
            float v = -expA * val;
#pragma unroll
            for (int off = 1; off < 64; off <<= 1) {
                float u = __shfl_up(v, off);
                if (lane >= off) v += u;
            }
            sL[tid] = v;
            float lt = __shfl(v, 63);
            sW[tid] = expf(lt - v);
            sRdt[tid] = 1.f / val;
        }
        {
            int r = tid >> 2, q = tid & 3;
            const short* cs = xb + (size_t)(t0 + r) * CD + DI + DSTATE + q * 32;
            const short* bs = xb + (size_t)(t0 + r) * CD + DI + q * 32;
#pragma unroll
            for (int j = 0; j < 4; j++) {
                *(bf16x8*)&CtL[r][q * 32 + j * 8] = *(const bf16x8*)(cs + j * 8);
                *(bf16x8*)&BtL[r][q * 32 + j * 8] = *(const bf16x8*)(bs + j * 8);
            }
        }
#pragma unroll
        for (int i = 0; i < 2; i++)
#pragma unroll
            for (int pq = 0; pq < 4; pq++) {
                int nb = wave * 32 + i * 16 + (l4 << 2);
                int p = pq * 16 + l16;
                *(short2*)&hL[p][nb] = make_short2(f2bs(acc_h[i][pq][0]), f2bs(acc_h[i][pq][1]));
                *(short2*)&hL[p][nb + 2] = make_short2(f2bs(acc_h[i][pq][2]), f2bs(acc_h[i][pq][3]));
            }
        __syncthreads();

        {
            int s = tid & 63, pg = tid >> 6;
            const short* xs = xb + (size_t)(t0 + s) * CD + hh * HD + pg * 16;
            float dts = sdt[s];
            float dw = dts * sW[s];
            bf16x8 v0 = *(const bf16x8*)xs;
            bf16x8 v1 = *(const bf16x8*)(xs + 8);
#pragma unroll
            for (int j = 0; j < 8; j++) {
                float xv = b2f(v0[j]);
                XdL[pg * 16 + j][s] = f2bs(xv * dts);
                XdwL[pg * 16 + j][s] = f2bs(xv * dw);
            }
#pragma unroll
            for (int j = 0; j < 8; j++) {
                float xv = b2f(v1[j]);
                XdL[pg * 16 + 8 + j][s] = f2bs(xv * dts);
                XdwL[pg * 16 + 8 + j][s] = f2bs(xv * dw);
            }
        }
        __syncthreads();

        {
            f32x4 g[2][2] = {};
#pragma unroll
            for (int ks = 0; ks < 4; ks++) {
                bf16x8 af[2], bfm[2];
#pragma unroll
                for (int i = 0; i < 2; i++)
                    af[i] = *(const bf16x8*)&CtL[tg * 32 + i * 16 + l16][ks * 32 + l4 * 8];
#pragma unroll
                for (int n = 0; n < 2; n++)
                    bfm[n] = *(const bf16x8*)&BtL[sg * 32 + n * 16 + l16][ks * 32 + l4 * 8];
#pragma unroll
                for (int i = 0; i < 2; i++)
#pragma unroll
                    for (int n = 0; n < 2; n++)
                        g[i][n] = __builtin_amdgcn_mfma_f32_16x16x32_bf16(af[i], bfm[n], g[i][n], 0, 0, 0);
            }
#pragma unroll
            for (int i = 0; i < 2; i++) {
                int tb2 = tg * 32 + i * 16 + (l4 << 2);
                float4 Lt = *(const float4*)&sL[tb2];
                float Ltr[4] = {Lt.x, Lt.y, Lt.z, Lt.w};
#pragma unroll
                for (int n = 0; n < 2; n++) {
                    int sE = sg * 32 + n * 16 + l16;
                    float Ls = sL[sE];
#pragma unroll
                    for (int r2 = 0; r2 < 4; r2++) {
                        float m = (sE <= tb2 + r2) ? g[i][n][r2] * expf(Ltr[r2] - Ls) : 0.f;
                        ML[tb2 + r2][sE] = f2bs(m);
                    }
                }
            }
        }
        __syncthreads();

        {
            f32x4 ay[2][2] = {};
            f32x4 ai[2][2] = {};
#pragma unroll
            for (int ks = 0; ks < 2; ks++) {
                bf16x8 af[2], bfp[2];
#pragma unroll
                for (int i = 0; i < 2; i++)
                    af[i] = *(const bf16x8*)&ML[tg * 32 + i * 16 + l16][ks * 32 + l4 * 8];
#pragma unroll
                for (int n = 0; n < 2; n++)
                    bfp[n] = *(const bf16x8*)&XdL[sg * 32 + n * 16 + l16][ks * 32 + l4 * 8];
#pragma unroll
                for (int i = 0; i < 2; i++)
#pragma unroll
                    for (int n = 0; n < 2; n++)
                        ay[i][n] = __builtin_amdgcn_mfma_f32_16x16x32_bf16(af[i], bfp[n], ay[i][n], 0, 0, 0);
            }
#pragma unroll
            for (int ks = 0; ks < 4; ks++) {
                bf16x8 af[2], bfh[2];
#pragma unroll
                for (int i = 0; i < 2; i++)
                    af[i] = *(const bf16x8*)&CtL[tg * 32 + i * 16 + l16][ks * 32 + l4 * 8];
#pragma unroll
                for (int n = 0; n < 2; n++) {
                    int prow = sg * 32 + n * 16 + l16;
                    int kb = ks * 32 + l4 * 8;
                    union { bf16x8 v; uint2 u2[2]; } hu;
                    hu.u2[0] = *(const uint2*)&hL[prow][kb];
                    hu.u2[1] = *(const uint2*)&hL[prow][kb + 4];
                    bfh[n] = hu.v;
                }
#pragma unroll
                for (int i = 0; i < 2; i++)
#pragma unroll
                    for (int n = 0; n < 2; n++)
                        ai[i][n] = __builtin_amdgcn_mfma_f32_16x16x32_bf16(af[i], bfh[n], ai[i][n], 0, 0, 0);
            }
            float Lft = sL[63];
#pragma unroll
            for (int i = 0; i < 2; i++) {
                int tb2 = tg * 32 + i * 16 + (l4 << 2);
                float4 Lt = *(const float4*)&sL[tb2];
                float4 Rt = *(const float4*)&sRdt[tb2];
                float Ltr[4] = {Lt.x, Lt.y, Lt.z, Lt.w};
                float Rtr[4] = {Rt.x, Rt.y, Rt.z, Rt.w};
#pragma unroll
                for (int n = 0; n < 2; n++) {
                    int p = sg * 32 + n * 16 + l16;
#pragma unroll
                    for (int r2 = 0; r2 < 4; r2++) {
                        float xv = b2f(XdL[p][tb2 + r2]) * Rtr[r2];
                        float yv = ay[i][n][r2] + expf(Ltr[r2]) * ai[i][n][r2] + Dh * xv;
                        yb[(size_t)(t0 + tb2 + r2) * DI + p] = f2bs(yv);
                    }
                }
            }
            float Pf = expf(Lft);
#pragma unroll
            for (int i = 0; i < 2; i++)
#pragma unroll
                for (int pq = 0; pq < 4; pq++)
                    acc_h[i][pq] *= Pf;
#pragma unroll
            for (int ks = 0; ks < 2; ks++) {
                bf16x8 af2[2], bfw[4];
#pragma unroll
                for (int i = 0; i < 2; i++) {
                    int nrow = wave * 32 + i * 16 + l16;
                    short e[8];
#pragma unroll
                    for (int j = 0; j < 8; j++)
                        e[j] = BtL[ks * 32 + l4 * 8 + j][nrow];
                    af2[i] = *(bf16x8*)e;
                }
#pragma unroll
                for (int pq = 0; pq < 4; pq++)
                    bfw[pq] = *(const bf16x8*)&XdwL[pq * 16 + l16][ks * 32 + l4 * 8];
#pragma unroll
                for (int i = 0; i < 2; i++)
#pragma unroll
                    for (int pq = 0; pq < 4; pq++)
                        acc_h[i][pq] = __builtin_amdgcn_mfma_f32_16x16x32_bf16(af2[i], bfw[pq], acc_h[i][pq], 0, 0, 0);
            }
        }
        __syncthreads();
    }
}

// ---------------- Kernel 6: gating + RMSNorm (bf16 y, bf16 z) -> bf16 g ----------------
__global__ __launch_bounds__(256) void gate_rms_kernel(const short* __restrict__ ybq,
                                                       const short* __restrict__ zx,
                                                       const float* __restrict__ rw,
                                                       __hip_bfloat16* __restrict__ gq) {
    int m = blockIdx.x;
    int tid = threadIdx.x;
    const short* yr = ybq + (size_t)m * DI;
    const short* zr = zx + (size_t)m * DIP;
    int base = tid * 8;
    float gv[8];
    float ss = 0.f;
    bf16x8 yv8 = *(const bf16x8*)(yr + base);
    bf16x8 zv8 = *(const bf16x8*)(zr + base);
#pragma unroll
    for (int i = 0; i < 8; i++) {
        float y = b2f(yv8[i]);
        float z = b2f(zv8[i]);
        float sg = 1.f / (1.f + expf(-z));
        float gg = y * z * sg;
        gv[i] = gg;
        ss += gg * gg;
    }
#pragma unroll
    for (int off = 1; off < 64; off <<= 1) ss += __shfl_xor(ss, off);
    __shared__ float red[4];
    int w = tid >> 6;
    if ((tid & 63) == 0) red[w] = ss;
    __syncthreads();
    float tot = red[0] + red[1] + red[2] + red[3];
    float r = rsqrtf(tot * (1.f / DI) + 1e-5f);
#pragma unroll
    for (int i = 0; i < 8; i += 2) {
        __hip_bfloat162 p;
        p.x = __float2bfloat16(gv[i] * r * rw[base + i]);
        p.y = __float2bfloat16(gv[i + 1] * r * rw[base + i + 1]);
        *(__hip_bfloat162*)(gq + (size_t)m * DI + base + i) = p;
    }
}

// ---------------- Kernel 7: GEMM2 bf16 MFMA (T2 swizzle + T1 remap m-inner, transposed store) ----------------
__global__ __launch_bounds__(256) void gemm2_mfma(const __hip_bfloat16* __restrict__ gq,
                                                  const __hip_bfloat16* __restrict__ Wob,
                                                  float* __restrict__ out) {
    __shared__ short As[128][64];
    __shared__ short Bs[128][64];
    int tid = threadIdx.x;
    int lane = tid & 63;
    int wave = tid >> 6;
    int wr = wave >> 1, wc = wave & 1;
    int id = blockIdx.x;
    int xcd = id & 7;
    int pos = id >> 3;
    int j0 = (pos >> 3) * 128;
    int m0 = (xcd * 8 + (pos & 7)) * 128;
    int srow = tid >> 3;
    int skc = (((tid & 7) ^ ((tid >> 3) & 7)) * 8);

    f32x4 acc[4][4] = {};

    for (int k0 = 0; k0 < DI; k0 += 64) {
        __syncthreads();
#pragma unroll
        for (int q = 0; q < 4; q++) {
            gload16(gq + (size_t)(m0 + q * 32 + srow) * DI + k0 + skc,
                    ((short*)As) + q * 2048 + wave * 512);
            gload16(Wob + (size_t)(j0 + q * 32 + srow) * DI + k0 + skc,
                    ((short*)Bs) + q * 2048 + wave * 512);
        }
        asm volatile("s_waitcnt vmcnt(0)" ::: "memory");
        __syncthreads();
#pragma unroll
        for (int ks = 0; ks < 2; ks++) {
            int pch = (((ks * 4) + (lane >> 4)) ^ (lane & 7)) * 8;
            bf16x8 af[4], bfr[4];
#pragma unroll
            for (int i = 0; i < 4; i++)
                af[i] = *(const bf16x8*)&As[wr * 64 + i * 16 + (lane & 15)][pch];
#pragma unroll
            for (int n = 0; n < 4; n++)
                bfr[n] = *(const bf16x8*)&Bs[wc * 64 + n * 16 + (lane & 15)][pch];
#pragma unroll
            for (int i = 0; i < 4; i++)
#pragma unroll
                for (int n = 0; n < 4; n++)
                    acc[i][n] = __builtin_amdgcn_mfma_f32_16x16x32_bf16(af[i], bfr[n], acc[i][n], 0, 0, 0);
        }
    }
#pragma unroll
    for (int i = 0; i < 4; i++) {
        int m = m0 + wr * 64 + i * 16 + ((lane >> 4) << 2);
        int b = m >> 12;
        int t = m & 4095;
#pragma unroll
        for (int n = 0; n < 4; n++) {
            int j = j0 + wc * 64 + n * 16 + (lane & 15);
            *(f32x4*)(out + (size_t)b * DM * TT + (size_t)j * TT + t) = acc[i][n];
        }
    }
}

extern "C" void kernel_launch(void* const* d_in, const int* in_sizes, int n_in,
                              void* d_out, int out_size, void* d_ws, size_t ws_size,
                              hipStream_t stream) {
    const float* x       = (const float*)d_in[0];
    const float* ln_w    = (const float*)d_in[1];
    const float* ln_b    = (const float*)d_in[2];
    const float* W_in    = (const float*)d_in[3];
    const float* conv_w  = (const float*)d_in[4];
    const float* conv_b  = (const float*)d_in[5];
    const float* dt_bias = (const float*)d_in[6];
    const float* A_log   = (const float*)d_in[7];
    const float* Dp      = (const float*)d_in[8];
    const float* rms_w   = (const float*)d_in[9];
    const float* W_out   = (const float*)d_in[10];
    const float* h0      = (const float*)d_in[11];

    float* out = (float*)d_out;
    float* hT = out + (size_t)BB * DM * TT;

    char* ws = (char*)d_ws;
    // Workspace layout — total 211,355,648 bytes:
    float* mu   = (float*)(ws + 0);
    float* rs   = (float*)(ws + 32768);
    short* zxq  = (short*)(ws + 65536);                   //  71,827,456  (B,T,4384) bf16
    short* xBCq = (short*)(ws + 71892992);                //  37,748,736  (B,T,2304) bf16
    __hip_bfloat16* gq  = (__hip_bfloat16*)(ws + 71892992);
    __hip_bfloat16* Wob = (__hip_bfloat16*)(ws + 105447424);
    short* ybq  = (short*)(ws + 109641728);               //  33,554,432  (B,T,2048) bf16
    __hip_bfloat16* Wb  = (__hip_bfloat16*)(ws + 109641728);
    float* dtv  = (float*)(ws + 176750592);
    __hip_bfloat16* xnb = (__hip_bfloat16*)(ws + 177799168);
    float* S    = (float*)(ws + 177799168);
    float* P    = (float*)(ws + 194576384);
    float* dpart = (float*)(ws + 194578432);              //  16,777,216

    ln_stats_kernel<<<(TT / 32) * BB, 256, 0, stream>>>(x, mu, rs);
    xn_kernel<<<dim3(TT / 64, DM / 64, BB), 256, 0, stream>>>(x, mu, rs, ln_w, ln_b, xnb);
    cvt_pad_kernel<<<(NP1 * DM) / 1024, 256, 0, stream>>>(W_in, Wb, DIP * DM, NP1 * DM);
    gemm1_mfma<<<(NP1 / 128) * ((BB * TT) / 128), 256, 0, stream>>>(Wb, xnb, zxq);
    gemm1_strip<<<dim3(KSPLIT, (BB * TT) / 64), 256, 0, stream>>>(x, mu, rs, ln_w, ln_b, W_in, dpart);
    dt_reduce_kernel<<<(BB * TT * NH) / 256, 256, 0, stream>>>(dpart, dt_bias, dtv);
    conv_kernel<<<(BB * (TT / 4) * (CD / 8)) / 256, 256, 0, stream>>>(zxq, conv_w, conv_b, xBCq);
    scan_reduce_ssd<<<dim3(NC, NH, BB), 256, 0, stream>>>(xBCq, dtv, A_log, S, P);
    scan_combine_kernel<<<(int)(SELEMS / 256), 256, 0, stream>>>(h0, P, S, hT);
    scan_emit_ssd<<<dim3(NC, NH, BB), 256, 0, stream>>>(xBCq, dtv, A_log, S, Dp, ybq);
    cvt_pad_kernel<<<(DM * DI) / 1024, 256, 0, stream>>>(W_out, Wob, DM * DI, DM * DI);
    gate_rms_kernel<<<BB * TT, 256, 0, stream>>>(ybq, zxq, rms_w, gq);
    gemm2_mfma<<<((BB * TT) / 128) * (DM / 128), 256, 0, stream>>>(gq, Wob, out);
}